// Round 5
// baseline (348.503 us; speedup 1.0000x reference)
//
#include <hip/hip_runtime.h>
#include <hip/hip_bf16.h>
#include <stdint.h>

#define NEGV -1e30f

typedef __attribute__((ext_vector_type(8))) __bf16 bf16x8;
typedef __attribute__((ext_vector_type(4))) float f32x4;

__device__ __forceinline__ uint16_t f2bfu(float f){
  __hip_bfloat16 h = __float2bfloat16(f);
  return *reinterpret_cast<const uint16_t*>(&h);
}

// ---------------- child part: K-split matvec partials. grid = 64 jb x 8 ks
__global__ __launch_bounds__(256) void k_child_part(
    const float* __restrict__ pf, const float* __restrict__ gc,
    const float* __restrict__ gn, const float* __restrict__ Wp,
    float* __restrict__ pchild)
{
  __shared__ float xs[36];
  int jb = blockIdx.x & 63, ks = blockIdx.x >> 6;
  int tid = threadIdx.x;
  int i0 = ks*36, i1 = (i0+36 < 282) ? i0+36 : 282;
  if (tid < i1-i0){
    int i = i0 + tid;
    xs[tid] = (i < 256) ? pf[i] : ((i < 272) ? gc[i-256] : gn[i-272]);
  }
  __syncthreads();
  int j0 = jb*1024 + tid*4;
  f32x4 acc = {0,0,0,0};
  #pragma unroll 6
  for (int i = i0; i < i1; ++i){
    f32x4 w = *reinterpret_cast<const f32x4*>(Wp + i*65536 + j0);
    float x = xs[i-i0];
    acc[0] = fmaf(x, w[0], acc[0]);
    acc[1] = fmaf(x, w[1], acc[1]);
    acc[2] = fmaf(x, w[2], acc[2]);
    acc[3] = fmaf(x, w[3], acc[3]);
  }
  *reinterpret_cast<f32x4*>(pchild + ks*65536 + j0) = acc;
}

// ---------------- child reduce: sum partials + bias + relu -> cf, cfcb slot 0
__global__ __launch_bounds__(256) void k_child_reduce(
  const float* __restrict__ pchild, const float* __restrict__ bp,
  float* __restrict__ cf, __hip_bfloat16* __restrict__ cfcb)
{
  int j = blockIdx.x*256 + threadIdx.x;
  float s = bp[j];
  #pragma unroll
  for (int ks = 0; ks < 8; ++ks) s += pchild[ks*65536 + j];
  s = fmaxf(s, 0.f);
  cf[j] = s;
  cfcb[(j>>8)*768 + (j&255)] = __float2bfloat16(s);
}

// ---------------- exists logits + node_ok + zero has_edges flag
__global__ __launch_bounds__(256) void k_exists(
  const float* __restrict__ cf, const float* __restrict__ Wex,
  const float* __restrict__ bex, float* __restrict__ exout,
  int* __restrict__ ok, int* __restrict__ flag)
{
  __shared__ float red[256];
  int m = blockIdx.x, tid = threadIdx.x;
  red[tid] = cf[m*256+tid]*Wex[tid];
  __syncthreads();
  for (int s = 128; s > 0; s >>= 1){ if (tid < s) red[tid] += red[tid+s]; __syncthreads(); }
  if (tid == 0){
    float logit = red[0] + bex[0];
    exout[m] = logit;
    ok[m] = logit > 0.f ? 1 : 0;
    if (m == 0) *flag = 0;
  }
}

// ---------------- a = cf@W_el[:H], b2 = cf@W_el[H:]  (fp32, row-blocked RB=4; also writes b2T)
__global__ __launch_bounds__(256) void k_ab(
  const float* __restrict__ cf, const float* __restrict__ Wel,
  float* __restrict__ a, float* __restrict__ b2, float* __restrict__ b2T)
{
  __shared__ float cfs[4][256];
  int bid = blockIdx.x; int sel = bid >> 6; int m0 = (bid & 63)*4; int tid = threadIdx.x;
  #pragma unroll
  for (int r = 0; r < 4; ++r) cfs[r][tid] = cf[(m0+r)*256 + tid];
  __syncthreads();
  const float* W = Wel + sel*65536;
  float acc0 = 0.f, acc1 = 0.f, acc2 = 0.f, acc3 = 0.f;
  #pragma unroll 8
  for (int j = 0; j < 256; ++j){
    float w = W[j*256+tid];
    acc0 = fmaf(cfs[0][j], w, acc0);
    acc1 = fmaf(cfs[1][j], w, acc1);
    acc2 = fmaf(cfs[2][j], w, acc2);
    acc3 = fmaf(cfs[3][j], w, acc3);
  }
  float* dst = sel ? b2 : a;
  dst[(m0+0)*256+tid] = acc0;
  dst[(m0+1)*256+tid] = acc1;
  dst[(m0+2)*256+tid] = acc2;
  dst[(m0+3)*256+tid] = acc3;
  if (sel){
    b2T[tid*256 + m0+0] = acc0;
    b2T[tid*256 + m0+1] = acc1;
    b2T[tid*256 + m0+2] = acc2;
    b2T[tid*256 + m0+3] = acc3;
  }
}

// ---------------- ee part: h-split 2. grid = m(256) x hs(2); partial e[4] per (m,n)
__global__ __launch_bounds__(256) void k_ee_part(
  const float* __restrict__ a, const float* __restrict__ b2T,
  const float* __restrict__ bel, const float* __restrict__ Wee,
  float* __restrict__ pee)
{
  __shared__ float wee[4][128];
  __shared__ float ac[128];
  int bid = blockIdx.x; int m = bid & 255; int hs = bid >> 8;
  int tid = threadIdx.x;
  int h0 = hs*128;
  if (tid < 128){
    ac[tid] = a[m*256 + h0 + tid] + bel[h0 + tid];
    wee[0][tid] = Wee[      h0 + tid];
    wee[1][tid] = Wee[256 + h0 + tid];
  } else {
    int t = tid - 128;
    wee[2][t] = Wee[512 + h0 + t];
    wee[3][t] = Wee[768 + h0 + t];
  }
  __syncthreads();
  int n = tid;
  float e0 = 0.f, e1 = 0.f, e2 = 0.f, e3 = 0.f;
  #pragma unroll 8
  for (int h = 0; h < 128; ++h){
    float el = fmaxf(ac[h] + b2T[(h0+h)*256 + n], 0.f);
    e0 = fmaf(el, wee[0][h], e0);
    e1 = fmaf(el, wee[1][h], e1);
    e2 = fmaf(el, wee[2][h], e2);
    e3 = fmaf(el, wee[3][h], e3);
  }
  f32x4 p; p[0]=e0; p[1]=e1; p[2]=e2; p[3]=e3;
  *reinterpret_cast<f32x4*>(pee + ((hs*256+m)*256 + n)*4) = p;
}

// ---------------- ee combine: bias + partials -> eeout, eemask, flag
__global__ __launch_bounds__(256) void k_ee_combine(
  const float* __restrict__ pee, const float* __restrict__ bee,
  const int* __restrict__ ok, float* __restrict__ eemask,
  float* __restrict__ eeout, int* __restrict__ flag)
{
  int m = blockIdx.x, n = threadIdx.x;
  f32x4 p0 = *reinterpret_cast<const f32x4*>(pee + ((0*256+m)*256 + n)*4);
  f32x4 p1 = *reinterpret_cast<const f32x4*>(pee + ((1*256+m)*256 + n)*4);
  float e0 = bee[0] + p0[0] + p1[0];
  float e1 = bee[1] + p0[1] + p1[1];
  float e2 = bee[2] + p0[2] + p1[2];
  float e3 = bee[3] + p0[3] + p1[3];
  int idx = (m*256+n)*4;
  f32x4 eo; eo[0]=e0; eo[1]=e1; eo[2]=e2; eo[3]=e3;
  *reinterpret_cast<f32x4*>(eeout + idx) = eo;
  int okmn = ok[m] & ok[n];
  f32x4 em;
  em[0] = (okmn && e0 > 0.f) ? e0 : NEGV;
  em[1] = (okmn && e1 > 0.f) ? e1 : NEGV;
  em[2] = (okmn && e2 > 0.f) ? e2 : NEGV;
  em[3] = (okmn && e3 > 0.f) ? e3 : NEGV;
  *reinterpret_cast<f32x4*>(eemask + idx) = em;
  if (em[0] > -1e29f || em[1] > -1e29f || em[2] > -1e29f || em[3] > -1e29f) atomicOr(flag, 1);
}

// ---------------- WeT[it][k][h] = bf16(W_ne[it][512+h][k])  (transpose for MFMA B-frags)
__global__ __launch_bounds__(256) void k_wet(const float* __restrict__ Wne,
                                             __hip_bfloat16* __restrict__ WeT)
{
  int bid = blockIdx.x; int i = bid >> 8, k = bid & 255, h = threadIdx.x;
  WeT[i*65536 + k*256 + h] = __float2bfloat16(Wne[i*197632 + (512+h)*256 + k]);
}

// ---------------- tiled fp32 -> bf16 transpose: out[N][K] = bf16(in[K][N]), 64x64 tiles
__global__ __launch_bounds__(256) void k_transpose_bf16(
  const float* __restrict__ in, __hip_bfloat16* __restrict__ out, int K, int N, int ktiles)
{
  __shared__ float t[64][65];
  int kt = blockIdx.x % ktiles, nt = blockIdx.x / ktiles;
  int k0 = kt*64, n0 = nt*64;
  int tid = threadIdx.x; int c = tid & 63, rg = tid >> 6;
  #pragma unroll
  for (int rr = 0; rr < 16; ++rr){
    int row = rg + rr*4;
    t[row][c] = in[(k0+row)*N + n0 + c];
  }
  __syncthreads();
  #pragma unroll
  for (int rr = 0; rr < 16; ++rr){
    int row = rg + rr*4;
    out[(n0+row)*K + k0 + c] = __float2bfloat16(t[c][row]);
  }
}

// ---------------- WsemT[64][256]: WsemT[c][j] = bf16(Wsem[j][c]) (pad c>=50 with 0)
__global__ __launch_bounds__(256) void k_wsem(const float* __restrict__ Wsem,
                                              __hip_bfloat16* __restrict__ WsemT)
{
  int tid = threadIdx.x;
  int j = blockIdx.x*4 + (tid>>6), c = tid & 63;
  float v = (c < 50) ? Wsem[j*50+c] : 0.f;
  WsemT[c*256 + j] = __float2bfloat16(v);
}

// ---------------- s'[m,k]=cf@Ws + b_ne ; d[n,k]=cf@Wd  (fp32, row-blocked RB=4)
__global__ __launch_bounds__(256) void k_sd(
  const float* __restrict__ cf, const float* __restrict__ Wne,
  const float* __restrict__ bne, float* __restrict__ sp, float* __restrict__ d, int it)
{
  __shared__ float cfs[4][256];
  int bid = blockIdx.x; int sel = bid >> 6; int m0 = (bid & 63)*4; int tid = threadIdx.x;
  #pragma unroll
  for (int r = 0; r < 4; ++r) cfs[r][tid] = cf[(m0+r)*256 + tid];
  __syncthreads();
  const float* W = Wne + it*197632 + sel*65536;
  float bias = sel ? 0.f : bne[it*256+tid];
  float acc0 = bias, acc1 = bias, acc2 = bias, acc3 = bias;
  #pragma unroll 8
  for (int j = 0; j < 256; ++j){
    float w = W[j*256+tid];
    acc0 = fmaf(cfs[0][j], w, acc0);
    acc1 = fmaf(cfs[1][j], w, acc1);
    acc2 = fmaf(cfs[2][j], w, acc2);
    acc3 = fmaf(cfs[3][j], w, acc3);
  }
  float* dst = sel ? d : sp;
  dst[(m0+0)*256+tid] = acc0;
  dst[(m0+1)*256+tid] = acc1;
  dst[(m0+2)*256+tid] = acc2;
  dst[(m0+3)*256+tid] = acc3;
}

// ---------------- fused per-iteration: el recompute -> MFMA E=el@We -> masked max
// grid = m(256) x kc(4). Block owns out[m, kc*64..+64); We^T chunk (64x256 bf16,
// XOR-swizzled) staged in LDS, shared by all 4 waves -> no B-frags in VGPRs.
// Wave w covers n in [w*64, w*64+64); cross-wave max via LDS; writes cf/cfcb.
__global__ __launch_bounds__(256,4) void k_fused(
  const float* __restrict__ a, const float* __restrict__ bel,
  const float* __restrict__ b2, const __hip_bfloat16* __restrict__ wet,
  const float* __restrict__ sp, const float* __restrict__ dmat,
  const float* __restrict__ eemask, const float* __restrict__ Wne_it,
  float* __restrict__ cf, __hip_bfloat16* __restrict__ cfcb,
  const int* __restrict__ flag, int it)
{
  __shared__ __attribute__((aligned(16))) char weS[32768]; // [64 k-rows][256 h] bf16, swizzled
  __shared__ float ac[256];
  __shared__ float red[4][64];
  int bid = blockIdx.x; int m = bid >> 2; int kc = bid & 3;
  int tid = threadIdx.x;
  ac[tid] = a[m*256+tid] + bel[tid];
  // stage We^T chunk: 2048 x 16B, swizzle byte ^= (row&7)<<4
  const char* wsrc = reinterpret_cast<const char*>(wet + kc*16384);
  #pragma unroll
  for (int p = 0; p < 8; ++p){
    int i = p*256 + tid;
    int row = i >> 5, colb = (i & 31) << 4;
    int byte = (row << 9) | colb;
    *reinterpret_cast<bf16x8*>(weS + (byte ^ ((row & 7) << 4))) =
      *reinterpret_cast<const bf16x8*>(wsrc + byte);
  }
  __syncthreads();

  int w = tid >> 6, l = tid & 63, l15 = l & 15, lg = l >> 4;
  float spv[4], wtv[4][4];
  #pragma unroll
  for (int kt = 0; kt < 4; ++kt){
    int kcol = kc*64 + kt*16 + l15;
    spv[kt] = sp[m*256+kcol];
    #pragma unroll
    for (int t = 0; t < 4; ++t) wtv[t][kt] = Wne_it[(768+t)*256 + kcol];
  }
  // per-kt LDS read bases (byte): row = kt*16+l15
  int rowb[4], rowx[4];
  #pragma unroll
  for (int kt = 0; kt < 4; ++kt){
    int row = kt*16 + l15;
    rowb[kt] = row << 9;
    rowx[kt] = (row & 7) << 4;
  }
  float runmax[4] = {NEGV, NEGV, NEGV, NEGV};

  for (int ni = 0; ni < 4; ++ni){
    int nb = w*64 + ni*16;
    // A-frags: el[nb+l15][kk*32+lg*8 .. +8] computed in-register
    bf16x8 Af[8];
    const float* b2r = b2 + (nb + l15)*256;
    #pragma unroll
    for (int kk = 0; kk < 8; ++kk){
      int h0 = kk*32 + lg*8;
      f32x4 bb0 = *reinterpret_cast<const f32x4*>(b2r + h0);
      f32x4 bb1 = *reinterpret_cast<const f32x4*>(b2r + h0 + 4);
      f32x4 aa0 = *reinterpret_cast<const f32x4*>(ac + h0);
      f32x4 aa1 = *reinterpret_cast<const f32x4*>(ac + h0 + 4);
      union { uint16_t u[8]; bf16x8 v; } fr;
      #pragma unroll
      for (int j = 0; j < 4; ++j){
        fr.u[j]   = f2bfu(fmaxf(aa0[j]+bb0[j], 0.f));
        fr.u[j+4] = f2bfu(fmaxf(aa1[j]+bb1[j], 0.f));
      }
      Af[kk] = fr.v;
    }
    f32x4 acc0 = {0,0,0,0}, acc1 = {0,0,0,0}, acc2 = {0,0,0,0}, acc3 = {0,0,0,0};
    #pragma unroll
    for (int kk = 0; kk < 8; ++kk){
      int c = kk*64 + lg*16;
      bf16x8 B0 = *reinterpret_cast<const bf16x8*>(weS + ((rowb[0] + c) ^ rowx[0]));
      bf16x8 B1 = *reinterpret_cast<const bf16x8*>(weS + ((rowb[1] + c) ^ rowx[1]));
      bf16x8 B2 = *reinterpret_cast<const bf16x8*>(weS + ((rowb[2] + c) ^ rowx[2]));
      bf16x8 B3 = *reinterpret_cast<const bf16x8*>(weS + ((rowb[3] + c) ^ rowx[3]));
      acc0 = __builtin_amdgcn_mfma_f32_16x16x32_bf16(Af[kk], B0, acc0, 0, 0, 0);
      acc1 = __builtin_amdgcn_mfma_f32_16x16x32_bf16(Af[kk], B1, acc1, 0, 0, 0);
      acc2 = __builtin_amdgcn_mfma_f32_16x16x32_bf16(Af[kk], B2, acc2, 0, 0, 0);
      acc3 = __builtin_amdgcn_mfma_f32_16x16x32_bf16(Af[kk], B3, acc3, 0, 0, 0);
    }
    // D layout: col = l15 (k_local), row = lg*4 + r (n_local)
    #pragma unroll
    for (int r = 0; r < 4; ++r){
      int n = nb + lg*4 + r;
      f32x4 me = *reinterpret_cast<const f32x4*>(eemask + (m*256+n)*4);
      const float* dr = dmat + n*256 + kc*64;
      float Ed0 = acc0[r] + dr[     l15] + spv[0];
      float Ed1 = acc1[r] + dr[16 + l15] + spv[1];
      float Ed2 = acc2[r] + dr[32 + l15] + spv[2];
      float Ed3 = acc3[r] + dr[48 + l15] + spv[3];
      #pragma unroll
      for (int t = 0; t < 4; ++t){
        if (me[t] > -1e29f){
          runmax[0] = fmaxf(runmax[0], fmaf(me[t], wtv[t][0], Ed0));
          runmax[1] = fmaxf(runmax[1], fmaf(me[t], wtv[t][1], Ed1));
          runmax[2] = fmaxf(runmax[2], fmaf(me[t], wtv[t][2], Ed2));
          runmax[3] = fmaxf(runmax[3], fmaf(me[t], wtv[t][3], Ed3));
        }
      }
    }
  }
  // reduce over lg (n-rows within wave), then across waves via LDS
  #pragma unroll
  for (int kt = 0; kt < 4; ++kt){
    float v = runmax[kt];
    v = fmaxf(v, __shfl_xor(v, 16));
    v = fmaxf(v, __shfl_xor(v, 32));
    if (l < 16) red[w][kt*16 + l] = v;
  }
  __syncthreads();
  if (tid < 64){
    float v = fmaxf(fmaxf(red[0][tid], red[1][tid]), fmaxf(red[2][tid], red[3][tid]));
    float nv = fmaxf(v, 0.f);
    int kcol = kc*64 + tid;
    float outv = (*flag) ? nv : cf[m*256+kcol];
    cf[m*256+kcol] = outv;
    cfcb[m*768 + 256*(it+1) + kcol] = __float2bfloat16(outv);
  }
}

// ---------------- final MFMA: ch = relu(cfc@Wch+b); feats = relu(ch@Wc2+b); sem = ch@Wsem+b
__global__ __launch_bounds__(256) void k_final_mfma(
  const __hip_bfloat16* __restrict__ cfcb, const __hip_bfloat16* __restrict__ WchT,
  const float* __restrict__ bch, const __hip_bfloat16* __restrict__ Wc2T,
  const float* __restrict__ bc2, const __hip_bfloat16* __restrict__ WsemT,
  const float* __restrict__ bsem, float* __restrict__ feats_out,
  float* __restrict__ sem_out)
{
  __shared__ char chs[8192];   // ch tile 16x256 bf16, XOR-swizzled
  int tid = threadIdx.x; int w = tid>>6, l = tid&63, l15 = l&15, lg = l>>4;
  int m0 = blockIdx.x*16;

  // phase 1: ch = relu(cfc @ Wch + bch), K=768
  f32x4 acc[4] = {{0,0,0,0},{0,0,0,0},{0,0,0,0},{0,0,0,0}};
  const __hip_bfloat16* Aptr = cfcb + (m0 + l15)*768;
  #pragma unroll 2
  for (int ks = 0; ks < 24; ++ks){
    int k0 = ks*32 + lg*8;
    bf16x8 Af = *reinterpret_cast<const bf16x8*>(Aptr + k0);
    #pragma unroll
    for (int nt = 0; nt < 4; ++nt){
      int col = w*64 + nt*16 + l15;
      bf16x8 Bf = *reinterpret_cast<const bf16x8*>(WchT + col*768 + k0);
      acc[nt] = __builtin_amdgcn_mfma_f32_16x16x32_bf16(Af, Bf, acc[nt], 0, 0, 0);
    }
  }
  #pragma unroll
  for (int nt = 0; nt < 4; ++nt){
    int col = w*64 + nt*16 + l15;
    float bias = bch[col];
    #pragma unroll
    for (int r = 0; r < 4; ++r){
      int row = lg*4 + r;
      float v = fmaxf(acc[nt][r] + bias, 0.f);
      int byte = ((row*256 + col)*2) ^ ((row&7)<<4);
      *reinterpret_cast<__hip_bfloat16*>(chs + byte) = __float2bfloat16(v);
    }
  }
  __syncthreads();

  // phase 2: feats = relu(ch@Wc2+bc2) [N=256], sem = ch@Wsem+bsem [N=64 padded]
  f32x4 accf[4] = {{0,0,0,0},{0,0,0,0},{0,0,0,0},{0,0,0,0}};
  f32x4 accs = {0,0,0,0};
  int cols_sem = w*16 + l15;
  #pragma unroll 2
  for (int ks = 0; ks < 8; ++ks){
    int k0 = ks*32 + lg*8;
    int byteA = (l15*512 + k0*2) ^ ((l15&7)<<4);
    bf16x8 Af = *reinterpret_cast<const bf16x8*>(chs + byteA);
    #pragma unroll
    for (int nt = 0; nt < 4; ++nt){
      int col = w*64 + nt*16 + l15;
      bf16x8 Bf = *reinterpret_cast<const bf16x8*>(Wc2T + col*256 + k0);
      accf[nt] = __builtin_amdgcn_mfma_f32_16x16x32_bf16(Af, Bf, accf[nt], 0, 0, 0);
    }
    bf16x8 Bs = *reinterpret_cast<const bf16x8*>(WsemT + cols_sem*256 + k0);
    accs = __builtin_amdgcn_mfma_f32_16x16x32_bf16(Af, Bs, accs, 0, 0, 0);
  }
  #pragma unroll
  for (int nt = 0; nt < 4; ++nt){
    int col = w*64 + nt*16 + l15;
    float bias = bc2[col];
    #pragma unroll
    for (int r = 0; r < 4; ++r){
      int row = m0 + lg*4 + r;
      feats_out[row*256 + col] = fmaxf(accf[nt][r] + bias, 0.f);
    }
  }
  if (cols_sem < 50){
    float bias = bsem[cols_sem];
    #pragma unroll
    for (int r = 0; r < 4; ++r){
      int row = m0 + lg*4 + r;
      sem_out[row*50 + cols_sem] = accs[r] + bias;
    }
  }
}

extern "C" void kernel_launch(void* const* d_in, const int* in_sizes, int n_in,
                              void* d_out, int out_size, void* d_ws, size_t ws_size,
                              hipStream_t stream)
{
  const float* pf  = (const float*)d_in[0];
  const float* gc  = (const float*)d_in[1];
  const float* gn  = (const float*)d_in[2];
  const float* Wp  = (const float*)d_in[3];
  const float* bp  = (const float*)d_in[4];
  const float* Wex = (const float*)d_in[5];
  const float* bex = (const float*)d_in[6];
  const float* Wsem= (const float*)d_in[7];
  const float* bsem= (const float*)d_in[8];
  const float* Wel = (const float*)d_in[9];
  const float* bel = (const float*)d_in[10];
  const float* Wee = (const float*)d_in[11];
  const float* bee = (const float*)d_in[12];
  const float* Wne = (const float*)d_in[13];
  const float* bne = (const float*)d_in[14];
  const float* Wch = (const float*)d_in[15];
  const float* bch = (const float*)d_in[16];
  const float* Wc2 = (const float*)d_in[17];
  const float* bc2 = (const float*)d_in[18];

  float* out = (float*)d_out;
  float* feats_out = out;             // 65536
  float* sem_out   = out + 65536;     // 12800
  float* ex_out    = out + 78336;     // 256
  float* ee_out    = out + 78592;     // 262144

  char* ws = (char*)d_ws;
  float* cf    = (float*)(ws);                       // 256 KB
  float* a_    = (float*)(ws + ( 256u<<10));         // 256 KB
  float* b2_   = (float*)(ws + ( 512u<<10));         // 256 KB
  float* b2T   = (float*)(ws + ( 768u<<10));         // 256 KB
  float* sp_   = (float*)(ws + (1024u<<10));         // 256 KB
  float* dmat  = (float*)(ws + (1280u<<10));         // 256 KB
  float* eem   = (float*)(ws + (1536u<<10));         // 1 MB
  __hip_bfloat16* WeT   = (__hip_bfloat16*)(ws + (2560u<<10)); // 256 KB
  __hip_bfloat16* cfcb  = (__hip_bfloat16*)(ws + (2816u<<10)); // 384 KB
  __hip_bfloat16* WchT  = (__hip_bfloat16*)(ws + (3200u<<10)); // 384 KB
  __hip_bfloat16* Wc2T  = (__hip_bfloat16*)(ws + (3584u<<10)); // 128 KB
  __hip_bfloat16* WsemT = (__hip_bfloat16*)(ws + (3712u<<10)); //  32 KB
  int* ok   = (int*)(ws + (3744u<<10));
  int* flag = ok + 256;
  // time-shared 2MB window: pchild (k_child), pee (k_ee)
  float* pchild = (float*)(ws + (3776u<<10));        // 2 MB
  float* pee    = pchild;                            // 2 MB

  k_child_part<<<512,256,0,stream>>>(pf,gc,gn,Wp,pchild);
  k_child_reduce<<<256,256,0,stream>>>(pchild,bp,cf,cfcb);

  // weight preps (after pchild consumed)
  k_wet<<<512,256,0,stream>>>(Wne,WeT);
  k_transpose_bf16<<<48,256,0,stream>>>(Wch, WchT, 768, 256, 12);
  k_transpose_bf16<<<16,256,0,stream>>>(Wc2, Wc2T, 256, 256, 4);
  k_wsem<<<64,256,0,stream>>>(Wsem, WsemT);

  k_exists<<<256,256,0,stream>>>(cf,Wex,bex,ex_out,ok,flag);
  k_ab<<<128,256,0,stream>>>(cf,Wel,a_,b2_,b2T);
  k_ee_part<<<512,256,0,stream>>>(a_,b2T,bel,Wee,pee);
  k_ee_combine<<<256,256,0,stream>>>(pee,bee,ok,eem,ee_out,flag);
  for (int it = 0; it < 2; ++it){
    k_sd<<<128,256,0,stream>>>(cf,Wne,bne,sp_,dmat,it);
    k_fused<<<1024,256,0,stream>>>(a_,bel,b2_,WeT + it*65536,sp_,dmat,eem,
                                   Wne + it*197632,cf,cfcb,flag,it);
  }
  k_final_mfma<<<16,256,0,stream>>>(cfcb,WchT,bch,Wc2T,bc2,WsemT,bsem,feats_out,sem_out);
}

// Round 6
// 338.546 us; speedup vs baseline: 1.0294x; 1.0294x over previous
//
#include <hip/hip_runtime.h>
#include <hip/hip_bf16.h>
#include <stdint.h>

#define NEGV -1e30f

typedef __attribute__((ext_vector_type(8))) __bf16 bf16x8;
typedef __attribute__((ext_vector_type(4))) float f32x4;

__device__ __forceinline__ uint16_t f2bfu(float f){
  __hip_bfloat16 h = __float2bfloat16(f);
  return *reinterpret_cast<const uint16_t*>(&h);
}

// ---------------- child part: K-split matvec partials. grid = 64 jb x 8 ks
__global__ __launch_bounds__(256) void k_child_part(
    const float* __restrict__ pf, const float* __restrict__ gc,
    const float* __restrict__ gn, const float* __restrict__ Wp,
    float* __restrict__ pchild)
{
  __shared__ float xs[36];
  int jb = blockIdx.x & 63, ks = blockIdx.x >> 6;
  int tid = threadIdx.x;
  int i0 = ks*36, i1 = (i0+36 < 282) ? i0+36 : 282;
  if (tid < i1-i0){
    int i = i0 + tid;
    xs[tid] = (i < 256) ? pf[i] : ((i < 272) ? gc[i-256] : gn[i-272]);
  }
  __syncthreads();
  int j0 = jb*1024 + tid*4;
  f32x4 acc = {0,0,0,0};
  #pragma unroll 6
  for (int i = i0; i < i1; ++i){
    f32x4 w = *reinterpret_cast<const f32x4*>(Wp + i*65536 + j0);
    float x = xs[i-i0];
    acc[0] = fmaf(x, w[0], acc[0]);
    acc[1] = fmaf(x, w[1], acc[1]);
    acc[2] = fmaf(x, w[2], acc[2]);
    acc[3] = fmaf(x, w[3], acc[3]);
  }
  *reinterpret_cast<f32x4*>(pchild + ks*65536 + j0) = acc;
}

// ---------------- child reduce: sum partials + bias + relu -> cf, cfcb slot 0
__global__ __launch_bounds__(256) void k_child_reduce(
  const float* __restrict__ pchild, const float* __restrict__ bp,
  float* __restrict__ cf, __hip_bfloat16* __restrict__ cfcb)
{
  int j = blockIdx.x*256 + threadIdx.x;
  float s = bp[j];
  #pragma unroll
  for (int ks = 0; ks < 8; ++ks) s += pchild[ks*65536 + j];
  s = fmaxf(s, 0.f);
  cf[j] = s;
  cfcb[(j>>8)*768 + (j&255)] = __float2bfloat16(s);
}

// ---------------- exists logits + node_ok + zero has_edges flag
__global__ __launch_bounds__(256) void k_exists(
  const float* __restrict__ cf, const float* __restrict__ Wex,
  const float* __restrict__ bex, float* __restrict__ exout,
  int* __restrict__ ok, int* __restrict__ flag)
{
  __shared__ float red[256];
  int m = blockIdx.x, tid = threadIdx.x;
  red[tid] = cf[m*256+tid]*Wex[tid];
  __syncthreads();
  for (int s = 128; s > 0; s >>= 1){ if (tid < s) red[tid] += red[tid+s]; __syncthreads(); }
  if (tid == 0){
    float logit = red[0] + bex[0];
    exout[m] = logit;
    ok[m] = logit > 0.f ? 1 : 0;
    if (m == 0) *flag = 0;
  }
}

// ---------------- a = cf@W_el[:H], b2 = cf@W_el[H:]  (fp32, row-blocked RB=4; also writes b2T)
__global__ __launch_bounds__(256) void k_ab(
  const float* __restrict__ cf, const float* __restrict__ Wel,
  float* __restrict__ a, float* __restrict__ b2, float* __restrict__ b2T)
{
  __shared__ float cfs[4][256];
  int bid = blockIdx.x; int sel = bid >> 6; int m0 = (bid & 63)*4; int tid = threadIdx.x;
  #pragma unroll
  for (int r = 0; r < 4; ++r) cfs[r][tid] = cf[(m0+r)*256 + tid];
  __syncthreads();
  const float* W = Wel + sel*65536;
  float acc0 = 0.f, acc1 = 0.f, acc2 = 0.f, acc3 = 0.f;
  #pragma unroll 8
  for (int j = 0; j < 256; ++j){
    float w = W[j*256+tid];
    acc0 = fmaf(cfs[0][j], w, acc0);
    acc1 = fmaf(cfs[1][j], w, acc1);
    acc2 = fmaf(cfs[2][j], w, acc2);
    acc3 = fmaf(cfs[3][j], w, acc3);
  }
  float* dst = sel ? b2 : a;
  dst[(m0+0)*256+tid] = acc0;
  dst[(m0+1)*256+tid] = acc1;
  dst[(m0+2)*256+tid] = acc2;
  dst[(m0+3)*256+tid] = acc3;
  if (sel){
    b2T[tid*256 + m0+0] = acc0;
    b2T[tid*256 + m0+1] = acc1;
    b2T[tid*256 + m0+2] = acc2;
    b2T[tid*256 + m0+3] = acc3;
  }
}

// ---------------- ee part: h-split 2. grid = m(256) x hs(2); partial e[4] per (m,n)
__global__ __launch_bounds__(256) void k_ee_part(
  const float* __restrict__ a, const float* __restrict__ b2T,
  const float* __restrict__ bel, const float* __restrict__ Wee,
  float* __restrict__ pee)
{
  __shared__ float wee[4][128];
  __shared__ float ac[128];
  int bid = blockIdx.x; int m = bid & 255; int hs = bid >> 8;
  int tid = threadIdx.x;
  int h0 = hs*128;
  if (tid < 128){
    ac[tid] = a[m*256 + h0 + tid] + bel[h0 + tid];
    wee[0][tid] = Wee[      h0 + tid];
    wee[1][tid] = Wee[256 + h0 + tid];
  } else {
    int t = tid - 128;
    wee[2][t] = Wee[512 + h0 + t];
    wee[3][t] = Wee[768 + h0 + t];
  }
  __syncthreads();
  int n = tid;
  float e0 = 0.f, e1 = 0.f, e2 = 0.f, e3 = 0.f;
  #pragma unroll 8
  for (int h = 0; h < 128; ++h){
    float el = fmaxf(ac[h] + b2T[(h0+h)*256 + n], 0.f);
    e0 = fmaf(el, wee[0][h], e0);
    e1 = fmaf(el, wee[1][h], e1);
    e2 = fmaf(el, wee[2][h], e2);
    e3 = fmaf(el, wee[3][h], e3);
  }
  f32x4 p; p[0]=e0; p[1]=e1; p[2]=e2; p[3]=e3;
  *reinterpret_cast<f32x4*>(pee + ((hs*256+m)*256 + n)*4) = p;
}

// ---------------- ee combine: bias + partials -> eeout, eemask, flag
__global__ __launch_bounds__(256) void k_ee_combine(
  const float* __restrict__ pee, const float* __restrict__ bee,
  const int* __restrict__ ok, float* __restrict__ eemask,
  float* __restrict__ eeout, int* __restrict__ flag)
{
  int m = blockIdx.x, n = threadIdx.x;
  f32x4 p0 = *reinterpret_cast<const f32x4*>(pee + ((0*256+m)*256 + n)*4);
  f32x4 p1 = *reinterpret_cast<const f32x4*>(pee + ((1*256+m)*256 + n)*4);
  float e0 = bee[0] + p0[0] + p1[0];
  float e1 = bee[1] + p0[1] + p1[1];
  float e2 = bee[2] + p0[2] + p1[2];
  float e3 = bee[3] + p0[3] + p1[3];
  int idx = (m*256+n)*4;
  f32x4 eo; eo[0]=e0; eo[1]=e1; eo[2]=e2; eo[3]=e3;
  *reinterpret_cast<f32x4*>(eeout + idx) = eo;
  int okmn = ok[m] & ok[n];
  f32x4 em;
  em[0] = (okmn && e0 > 0.f) ? e0 : NEGV;
  em[1] = (okmn && e1 > 0.f) ? e1 : NEGV;
  em[2] = (okmn && e2 > 0.f) ? e2 : NEGV;
  em[3] = (okmn && e3 > 0.f) ? e3 : NEGV;
  *reinterpret_cast<f32x4*>(eemask + idx) = em;
  if (em[0] > -1e29f || em[1] > -1e29f || em[2] > -1e29f || em[3] > -1e29f) atomicOr(flag, 1);
}

// ---------------- WeT[it][k][h] = bf16(W_ne[it][512+h][k])  (transpose for MFMA B-frags)
__global__ __launch_bounds__(256) void k_wet(const float* __restrict__ Wne,
                                             __hip_bfloat16* __restrict__ WeT)
{
  int bid = blockIdx.x; int i = bid >> 8, k = bid & 255, h = threadIdx.x;
  WeT[i*65536 + k*256 + h] = __float2bfloat16(Wne[i*197632 + (512+h)*256 + k]);
}

// ---------------- tiled fp32 -> bf16 transpose: out[N][K] = bf16(in[K][N]), 64x64 tiles
__global__ __launch_bounds__(256) void k_transpose_bf16(
  const float* __restrict__ in, __hip_bfloat16* __restrict__ out, int K, int N, int ktiles)
{
  __shared__ float t[64][65];
  int kt = blockIdx.x % ktiles, nt = blockIdx.x / ktiles;
  int k0 = kt*64, n0 = nt*64;
  int tid = threadIdx.x; int c = tid & 63, rg = tid >> 6;
  #pragma unroll
  for (int rr = 0; rr < 16; ++rr){
    int row = rg + rr*4;
    t[row][c] = in[(k0+row)*N + n0 + c];
  }
  __syncthreads();
  #pragma unroll
  for (int rr = 0; rr < 16; ++rr){
    int row = rg + rr*4;
    out[(n0+row)*K + k0 + c] = __float2bfloat16(t[c][row]);
  }
}

// ---------------- WsemT[64][256]: WsemT[c][j] = bf16(Wsem[j][c]) (pad c>=50 with 0)
__global__ __launch_bounds__(256) void k_wsem(const float* __restrict__ Wsem,
                                              __hip_bfloat16* __restrict__ WsemT)
{
  int tid = threadIdx.x;
  int j = blockIdx.x*4 + (tid>>6), c = tid & 63;
  float v = (c < 50) ? Wsem[j*50+c] : 0.f;
  WsemT[c*256 + j] = __float2bfloat16(v);
}

// ---------------- s'[m,k]=cf@Ws + b_ne ; d[n,k]=cf@Wd  (fp32, row-blocked RB=4)
__global__ __launch_bounds__(256) void k_sd(
  const float* __restrict__ cf, const float* __restrict__ Wne,
  const float* __restrict__ bne, float* __restrict__ sp, float* __restrict__ d, int it)
{
  __shared__ float cfs[4][256];
  int bid = blockIdx.x; int sel = bid >> 6; int m0 = (bid & 63)*4; int tid = threadIdx.x;
  #pragma unroll
  for (int r = 0; r < 4; ++r) cfs[r][tid] = cf[(m0+r)*256 + tid];
  __syncthreads();
  const float* W = Wne + it*197632 + sel*65536;
  float bias = sel ? 0.f : bne[it*256+tid];
  float acc0 = bias, acc1 = bias, acc2 = bias, acc3 = bias;
  #pragma unroll 8
  for (int j = 0; j < 256; ++j){
    float w = W[j*256+tid];
    acc0 = fmaf(cfs[0][j], w, acc0);
    acc1 = fmaf(cfs[1][j], w, acc1);
    acc2 = fmaf(cfs[2][j], w, acc2);
    acc3 = fmaf(cfs[3][j], w, acc3);
  }
  float* dst = sel ? d : sp;
  dst[(m0+0)*256+tid] = acc0;
  dst[(m0+1)*256+tid] = acc1;
  dst[(m0+2)*256+tid] = acc2;
  dst[(m0+3)*256+tid] = acc3;
}

// ---------------- fused per-iteration: el recompute -> MFMA E=el@We -> masked max
// grid = m(256) x kc(4). Block owns out[m, kc*64..+64); We^T chunk (64x256 bf16,
// XOR-swizzled) in LDS shared by 4 waves. Wave w covers n in [w*64, w*64+64).
// Af built transiently per kk (8 regs live) to keep VGPR pressure ~110.
__global__ __launch_bounds__(256,3) void k_fused(
  const float* __restrict__ a, const float* __restrict__ bel,
  const float* __restrict__ b2, const __hip_bfloat16* __restrict__ wet,
  const float* __restrict__ sp, const float* __restrict__ dmat,
  const float* __restrict__ eemask, const float* __restrict__ Wne_it,
  float* __restrict__ cf, __hip_bfloat16* __restrict__ cfcb,
  const int* __restrict__ flag, int it)
{
  __shared__ __attribute__((aligned(16))) char weS[32768]; // [64 k-rows][256 h] bf16, swizzled
  __shared__ float ac[256];
  __shared__ float red[4][64];
  int bid = blockIdx.x; int m = bid >> 2; int kc = bid & 3;
  int tid = threadIdx.x;
  ac[tid] = a[m*256+tid] + bel[tid];
  // stage We^T chunk: 2048 x 16B, swizzle byte ^= (row&7)<<4
  const char* wsrc = reinterpret_cast<const char*>(wet + kc*16384);
  #pragma unroll
  for (int p = 0; p < 8; ++p){
    int i = p*256 + tid;
    int row = i >> 5, colb = (i & 31) << 4;
    int byte = (row << 9) | colb;
    *reinterpret_cast<bf16x8*>(weS + (byte ^ ((row & 7) << 4))) =
      *reinterpret_cast<const bf16x8*>(wsrc + byte);
  }
  __syncthreads();

  int w = tid >> 6, l = tid & 63, l15 = l & 15, lg = l >> 4;
  float spv[4], wtv[4][4];
  #pragma unroll
  for (int kt = 0; kt < 4; ++kt){
    int kcol = kc*64 + kt*16 + l15;
    spv[kt] = sp[m*256+kcol];
    #pragma unroll
    for (int t = 0; t < 4; ++t) wtv[t][kt] = Wne_it[(768+t)*256 + kcol];
  }
  // per-kt LDS read bases (byte): row = kt*16+l15
  int rowb[4], rowx[4];
  #pragma unroll
  for (int kt = 0; kt < 4; ++kt){
    int row = kt*16 + l15;
    rowb[kt] = row << 9;
    rowx[kt] = (row & 7) << 4;
  }
  float runmax[4] = {NEGV, NEGV, NEGV, NEGV};

  for (int ni = 0; ni < 4; ++ni){
    int nb = w*64 + ni*16;
    const float* b2r = b2 + (nb + l15)*256;
    f32x4 acc0 = {0,0,0,0}, acc1 = {0,0,0,0}, acc2 = {0,0,0,0}, acc3 = {0,0,0,0};
    #pragma unroll
    for (int kk = 0; kk < 8; ++kk){
      // transient A-frag: el[nb+l15][kk*32+lg*8 .. +8]
      int h0 = kk*32 + lg*8;
      f32x4 bb0 = *reinterpret_cast<const f32x4*>(b2r + h0);
      f32x4 bb1 = *reinterpret_cast<const f32x4*>(b2r + h0 + 4);
      f32x4 aa0 = *reinterpret_cast<const f32x4*>(ac + h0);
      f32x4 aa1 = *reinterpret_cast<const f32x4*>(ac + h0 + 4);
      union { uint16_t u[8]; bf16x8 v; } fr;
      #pragma unroll
      for (int j = 0; j < 4; ++j){
        fr.u[j]   = f2bfu(fmaxf(aa0[j]+bb0[j], 0.f));
        fr.u[j+4] = f2bfu(fmaxf(aa1[j]+bb1[j], 0.f));
      }
      int c = kk*64 + lg*16;
      bf16x8 B0 = *reinterpret_cast<const bf16x8*>(weS + ((rowb[0] + c) ^ rowx[0]));
      bf16x8 B1 = *reinterpret_cast<const bf16x8*>(weS + ((rowb[1] + c) ^ rowx[1]));
      bf16x8 B2 = *reinterpret_cast<const bf16x8*>(weS + ((rowb[2] + c) ^ rowx[2]));
      bf16x8 B3 = *reinterpret_cast<const bf16x8*>(weS + ((rowb[3] + c) ^ rowx[3]));
      acc0 = __builtin_amdgcn_mfma_f32_16x16x32_bf16(fr.v, B0, acc0, 0, 0, 0);
      acc1 = __builtin_amdgcn_mfma_f32_16x16x32_bf16(fr.v, B1, acc1, 0, 0, 0);
      acc2 = __builtin_amdgcn_mfma_f32_16x16x32_bf16(fr.v, B2, acc2, 0, 0, 0);
      acc3 = __builtin_amdgcn_mfma_f32_16x16x32_bf16(fr.v, B3, acc3, 0, 0, 0);
    }
    // D layout: col = l15 (k_local), row = lg*4 + r (n_local)
    #pragma unroll
    for (int r = 0; r < 4; ++r){
      int n = nb + lg*4 + r;
      f32x4 me = *reinterpret_cast<const f32x4*>(eemask + (m*256+n)*4);
      const float* dr = dmat + n*256 + kc*64;
      float Ed0 = acc0[r] + dr[     l15] + spv[0];
      float Ed1 = acc1[r] + dr[16 + l15] + spv[1];
      float Ed2 = acc2[r] + dr[32 + l15] + spv[2];
      float Ed3 = acc3[r] + dr[48 + l15] + spv[3];
      #pragma unroll
      for (int t = 0; t < 4; ++t){
        if (me[t] > -1e29f){
          runmax[0] = fmaxf(runmax[0], fmaf(me[t], wtv[t][0], Ed0));
          runmax[1] = fmaxf(runmax[1], fmaf(me[t], wtv[t][1], Ed1));
          runmax[2] = fmaxf(runmax[2], fmaf(me[t], wtv[t][2], Ed2));
          runmax[3] = fmaxf(runmax[3], fmaf(me[t], wtv[t][3], Ed3));
        }
      }
    }
  }
  // reduce over lg (n-rows within wave), then across waves via LDS
  #pragma unroll
  for (int kt = 0; kt < 4; ++kt){
    float v = runmax[kt];
    v = fmaxf(v, __shfl_xor(v, 16));
    v = fmaxf(v, __shfl_xor(v, 32));
    if (l < 16) red[w][kt*16 + l] = v;
  }
  __syncthreads();
  if (tid < 64){
    float v = fmaxf(fmaxf(red[0][tid], red[1][tid]), fmaxf(red[2][tid], red[3][tid]));
    float nv = fmaxf(v, 0.f);
    int kcol = kc*64 + tid;
    float outv = (*flag) ? nv : cf[m*256+kcol];
    cf[m*256+kcol] = outv;
    cfcb[m*768 + 256*(it+1) + kcol] = __float2bfloat16(outv);
  }
}

// ---------------- final MFMA: ch = relu(cfc@Wch+b); feats = relu(ch@Wc2+b); sem = ch@Wsem+b
__global__ __launch_bounds__(256) void k_final_mfma(
  const __hip_bfloat16* __restrict__ cfcb, const __hip_bfloat16* __restrict__ WchT,
  const float* __restrict__ bch, const __hip_bfloat16* __restrict__ Wc2T,
  const float* __restrict__ bc2, const __hip_bfloat16* __restrict__ WsemT,
  const float* __restrict__ bsem, float* __restrict__ feats_out,
  float* __restrict__ sem_out)
{
  __shared__ char chs[8192];   // ch tile 16x256 bf16, XOR-swizzled
  int tid = threadIdx.x; int w = tid>>6, l = tid&63, l15 = l&15, lg = l>>4;
  int m0 = blockIdx.x*16;

  // phase 1: ch = relu(cfc @ Wch + bch), K=768
  f32x4 acc[4] = {{0,0,0,0},{0,0,0,0},{0,0,0,0},{0,0,0,0}};
  const __hip_bfloat16* Aptr = cfcb + (m0 + l15)*768;
  #pragma unroll 2
  for (int ks = 0; ks < 24; ++ks){
    int k0 = ks*32 + lg*8;
    bf16x8 Af = *reinterpret_cast<const bf16x8*>(Aptr + k0);
    #pragma unroll
    for (int nt = 0; nt < 4; ++nt){
      int col = w*64 + nt*16 + l15;
      bf16x8 Bf = *reinterpret_cast<const bf16x8*>(WchT + col*768 + k0);
      acc[nt] = __builtin_amdgcn_mfma_f32_16x16x32_bf16(Af, Bf, acc[nt], 0, 0, 0);
    }
  }
  #pragma unroll
  for (int nt = 0; nt < 4; ++nt){
    int col = w*64 + nt*16 + l15;
    float bias = bch[col];
    #pragma unroll
    for (int r = 0; r < 4; ++r){
      int row = lg*4 + r;
      float v = fmaxf(acc[nt][r] + bias, 0.f);
      int byte = ((row*256 + col)*2) ^ ((row&7)<<4);
      *reinterpret_cast<__hip_bfloat16*>(chs + byte) = __float2bfloat16(v);
    }
  }
  __syncthreads();

  // phase 2: feats = relu(ch@Wc2+bc2) [N=256], sem = ch@Wsem+bsem [N=64 padded]
  f32x4 accf[4] = {{0,0,0,0},{0,0,0,0},{0,0,0,0},{0,0,0,0}};
  f32x4 accs = {0,0,0,0};
  int cols_sem = w*16 + l15;
  #pragma unroll 2
  for (int ks = 0; ks < 8; ++ks){
    int k0 = ks*32 + lg*8;
    int byteA = (l15*512 + k0*2) ^ ((l15&7)<<4);
    bf16x8 Af = *reinterpret_cast<const bf16x8*>(chs + byteA);
    #pragma unroll
    for (int nt = 0; nt < 4; ++nt){
      int col = w*64 + nt*16 + l15;
      bf16x8 Bf = *reinterpret_cast<const bf16x8*>(Wc2T + col*256 + k0);
      accf[nt] = __builtin_amdgcn_mfma_f32_16x16x32_bf16(Af, Bf, accf[nt], 0, 0, 0);
    }
    bf16x8 Bs = *reinterpret_cast<const bf16x8*>(WsemT + cols_sem*256 + k0);
    accs = __builtin_amdgcn_mfma_f32_16x16x32_bf16(Af, Bs, accs, 0, 0, 0);
  }
  #pragma unroll
  for (int nt = 0; nt < 4; ++nt){
    int col = w*64 + nt*16 + l15;
    float bias = bc2[col];
    #pragma unroll
    for (int r = 0; r < 4; ++r){
      int row = m0 + lg*4 + r;
      feats_out[row*256 + col] = fmaxf(accf[nt][r] + bias, 0.f);
    }
  }
  if (cols_sem < 50){
    float bias = bsem[cols_sem];
    #pragma unroll
    for (int r = 0; r < 4; ++r){
      int row = m0 + lg*4 + r;
      sem_out[row*50 + cols_sem] = accs[r] + bias;
    }
  }
}

extern "C" void kernel_launch(void* const* d_in, const int* in_sizes, int n_in,
                              void* d_out, int out_size, void* d_ws, size_t ws_size,
                              hipStream_t stream)
{
  const float* pf  = (const float*)d_in[0];
  const float* gc  = (const float*)d_in[1];
  const float* gn  = (const float*)d_in[2];
  const float* Wp  = (const float*)d_in[3];
  const float* bp  = (const float*)d_in[4];
  const float* Wex = (const float*)d_in[5];
  const float* bex = (const float*)d_in[6];
  const float* Wsem= (const float*)d_in[7];
  const float* bsem= (const float*)d_in[8];
  const float* Wel = (const float*)d_in[9];
  const float* bel = (const float*)d_in[10];
  const float* Wee = (const float*)d_in[11];
  const float* bee = (const float*)d_in[12];
  const float* Wne = (const float*)d_in[13];
  const float* bne = (const float*)d_in[14];
  const float* Wch = (const float*)d_in[15];
  const float* bch = (const float*)d_in[16];
  const float* Wc2 = (const float*)d_in[17];
  const float* bc2 = (const float*)d_in[18];

  float* out = (float*)d_out;
  float* feats_out = out;             // 65536
  float* sem_out   = out + 65536;     // 12800
  float* ex_out    = out + 78336;     // 256
  float* ee_out    = out + 78592;     // 262144

  char* ws = (char*)d_ws;
  float* cf    = (float*)(ws);                       // 256 KB
  float* a_    = (float*)(ws + ( 256u<<10));         // 256 KB
  float* b2_   = (float*)(ws + ( 512u<<10));         // 256 KB
  float* b2T   = (float*)(ws + ( 768u<<10));         // 256 KB
  float* sp_   = (float*)(ws + (1024u<<10));         // 256 KB
  float* dmat  = (float*)(ws + (1280u<<10));         // 256 KB
  float* eem   = (float*)(ws + (1536u<<10));         // 1 MB
  __hip_bfloat16* WeT   = (__hip_bfloat16*)(ws + (2560u<<10)); // 256 KB
  __hip_bfloat16* cfcb  = (__hip_bfloat16*)(ws + (2816u<<10)); // 384 KB
  __hip_bfloat16* WchT  = (__hip_bfloat16*)(ws + (3200u<<10)); // 384 KB
  __hip_bfloat16* Wc2T  = (__hip_bfloat16*)(ws + (3584u<<10)); // 128 KB
  __hip_bfloat16* WsemT = (__hip_bfloat16*)(ws + (3712u<<10)); //  32 KB
  int* ok   = (int*)(ws + (3744u<<10));
  int* flag = ok + 256;
  // time-shared 2MB window: pchild (k_child), pee (k_ee)
  float* pchild = (float*)(ws + (3776u<<10));        // 2 MB
  float* pee    = pchild;                            // 2 MB

  k_child_part<<<512,256,0,stream>>>(pf,gc,gn,Wp,pchild);
  k_child_reduce<<<256,256,0,stream>>>(pchild,bp,cf,cfcb);

  // weight preps (after pchild consumed)
  k_wet<<<512,256,0,stream>>>(Wne,WeT);
  k_transpose_bf16<<<48,256,0,stream>>>(Wch, WchT, 768, 256, 12);
  k_transpose_bf16<<<16,256,0,stream>>>(Wc2, Wc2T, 256, 256, 4);
  k_wsem<<<64,256,0,stream>>>(Wsem, WsemT);

  k_exists<<<256,256,0,stream>>>(cf,Wex,bex,ex_out,ok,flag);
  k_ab<<<128,256,0,stream>>>(cf,Wel,a_,b2_,b2T);
  k_ee_part<<<512,256,0,stream>>>(a_,b2T,bel,Wee,pee);
  k_ee_combine<<<256,256,0,stream>>>(pee,bee,ok,eem,ee_out,flag);
  for (int it = 0; it < 2; ++it){
    k_sd<<<128,256,0,stream>>>(cf,Wne,bne,sp_,dmat,it);
    k_fused<<<1024,256,0,stream>>>(a_,bel,b2_,WeT + it*65536,sp_,dmat,eem,
                                   Wne + it*197632,cf,cfcb,flag,it);
  }
  k_final_mfma<<<16,256,0,stream>>>(cfcb,WchT,bch,Wc2T,bc2,WsemT,bsem,feats_out,sem_out);
}

// Round 7
// 201.095 us; speedup vs baseline: 1.7330x; 1.6835x over previous
//
#include <hip/hip_runtime.h>
#include <hip/hip_bf16.h>
#include <stdint.h>

#define NEGV -1e30f

typedef __attribute__((ext_vector_type(8))) __bf16 bf16x8;
typedef __attribute__((ext_vector_type(4))) float f32x4;

__device__ __forceinline__ uint16_t f2bfu(float f){
  __hip_bfloat16 h = __float2bfloat16(f);
  return *reinterpret_cast<const uint16_t*>(&h);
}

// ---------------- child part: K-split matvec partials. grid = 64 jb x 8 ks
__global__ __launch_bounds__(256) void k_child_part(
    const float* __restrict__ pf, const float* __restrict__ gc,
    const float* __restrict__ gn, const float* __restrict__ Wp,
    float* __restrict__ pchild)
{
  __shared__ float xs[36];
  int jb = blockIdx.x & 63, ks = blockIdx.x >> 6;
  int tid = threadIdx.x;
  int i0 = ks*36, i1 = (i0+36 < 282) ? i0+36 : 282;
  if (tid < i1-i0){
    int i = i0 + tid;
    xs[tid] = (i < 256) ? pf[i] : ((i < 272) ? gc[i-256] : gn[i-272]);
  }
  __syncthreads();
  int j0 = jb*1024 + tid*4;
  f32x4 acc = {0,0,0,0};
  #pragma unroll 6
  for (int i = i0; i < i1; ++i){
    f32x4 w = *reinterpret_cast<const f32x4*>(Wp + i*65536 + j0);
    float x = xs[i-i0];
    acc[0] = fmaf(x, w[0], acc[0]);
    acc[1] = fmaf(x, w[1], acc[1]);
    acc[2] = fmaf(x, w[2], acc[2]);
    acc[3] = fmaf(x, w[3], acc[3]);
  }
  *reinterpret_cast<f32x4*>(pchild + ks*65536 + j0) = acc;
}

// ---------------- child reduce: sum partials + bias + relu -> cf, cfcb slot 0
__global__ __launch_bounds__(256) void k_child_reduce(
  const float* __restrict__ pchild, const float* __restrict__ bp,
  float* __restrict__ cf, __hip_bfloat16* __restrict__ cfcb)
{
  int j = blockIdx.x*256 + threadIdx.x;
  float s = bp[j];
  #pragma unroll
  for (int ks = 0; ks < 8; ++ks) s += pchild[ks*65536 + j];
  s = fmaxf(s, 0.f);
  cf[j] = s;
  cfcb[(j>>8)*768 + (j&255)] = __float2bfloat16(s);
}

// ---------------- exists logits + node_ok + zero has_edges flag
__global__ __launch_bounds__(256) void k_exists(
  const float* __restrict__ cf, const float* __restrict__ Wex,
  const float* __restrict__ bex, float* __restrict__ exout,
  int* __restrict__ ok, int* __restrict__ flag)
{
  __shared__ float red[256];
  int m = blockIdx.x, tid = threadIdx.x;
  red[tid] = cf[m*256+tid]*Wex[tid];
  __syncthreads();
  for (int s = 128; s > 0; s >>= 1){ if (tid < s) red[tid] += red[tid+s]; __syncthreads(); }
  if (tid == 0){
    float logit = red[0] + bex[0];
    exout[m] = logit;
    ok[m] = logit > 0.f ? 1 : 0;
    if (m == 0) *flag = 0;
  }
}

// ---------------- a = cf@W_el[:H], b2 = cf@W_el[H:]  (fp32, row-blocked RB=4; also writes b2T)
__global__ __launch_bounds__(256) void k_ab(
  const float* __restrict__ cf, const float* __restrict__ Wel,
  float* __restrict__ a, float* __restrict__ b2, float* __restrict__ b2T)
{
  __shared__ float cfs[4][256];
  int bid = blockIdx.x; int sel = bid >> 6; int m0 = (bid & 63)*4; int tid = threadIdx.x;
  #pragma unroll
  for (int r = 0; r < 4; ++r) cfs[r][tid] = cf[(m0+r)*256 + tid];
  __syncthreads();
  const float* W = Wel + sel*65536;
  float acc0 = 0.f, acc1 = 0.f, acc2 = 0.f, acc3 = 0.f;
  #pragma unroll 8
  for (int j = 0; j < 256; ++j){
    float w = W[j*256+tid];
    acc0 = fmaf(cfs[0][j], w, acc0);
    acc1 = fmaf(cfs[1][j], w, acc1);
    acc2 = fmaf(cfs[2][j], w, acc2);
    acc3 = fmaf(cfs[3][j], w, acc3);
  }
  float* dst = sel ? b2 : a;
  dst[(m0+0)*256+tid] = acc0;
  dst[(m0+1)*256+tid] = acc1;
  dst[(m0+2)*256+tid] = acc2;
  dst[(m0+3)*256+tid] = acc3;
  if (sel){
    b2T[tid*256 + m0+0] = acc0;
    b2T[tid*256 + m0+1] = acc1;
    b2T[tid*256 + m0+2] = acc2;
    b2T[tid*256 + m0+3] = acc3;
  }
}

// ---------------- ee part: h-split 2. grid = m(256) x hs(2); partial e[4] per (m,n)
__global__ __launch_bounds__(256) void k_ee_part(
  const float* __restrict__ a, const float* __restrict__ b2T,
  const float* __restrict__ bel, const float* __restrict__ Wee,
  float* __restrict__ pee)
{
  __shared__ float wee[4][128];
  __shared__ float ac[128];
  int bid = blockIdx.x; int m = bid & 255; int hs = bid >> 8;
  int tid = threadIdx.x;
  int h0 = hs*128;
  if (tid < 128){
    ac[tid] = a[m*256 + h0 + tid] + bel[h0 + tid];
    wee[0][tid] = Wee[      h0 + tid];
    wee[1][tid] = Wee[256 + h0 + tid];
  } else {
    int t = tid - 128;
    wee[2][t] = Wee[512 + h0 + t];
    wee[3][t] = Wee[768 + h0 + t];
  }
  __syncthreads();
  int n = tid;
  float e0 = 0.f, e1 = 0.f, e2 = 0.f, e3 = 0.f;
  #pragma unroll 8
  for (int h = 0; h < 128; ++h){
    float el = fmaxf(ac[h] + b2T[(h0+h)*256 + n], 0.f);
    e0 = fmaf(el, wee[0][h], e0);
    e1 = fmaf(el, wee[1][h], e1);
    e2 = fmaf(el, wee[2][h], e2);
    e3 = fmaf(el, wee[3][h], e3);
  }
  f32x4 p; p[0]=e0; p[1]=e1; p[2]=e2; p[3]=e3;
  *reinterpret_cast<f32x4*>(pee + ((hs*256+m)*256 + n)*4) = p;
}

// ---------------- ee combine: bias + partials -> eeout, eemask, flag
__global__ __launch_bounds__(256) void k_ee_combine(
  const float* __restrict__ pee, const float* __restrict__ bee,
  const int* __restrict__ ok, float* __restrict__ eemask,
  float* __restrict__ eeout, int* __restrict__ flag)
{
  int m = blockIdx.x, n = threadIdx.x;
  f32x4 p0 = *reinterpret_cast<const f32x4*>(pee + ((0*256+m)*256 + n)*4);
  f32x4 p1 = *reinterpret_cast<const f32x4*>(pee + ((1*256+m)*256 + n)*4);
  float e0 = bee[0] + p0[0] + p1[0];
  float e1 = bee[1] + p0[1] + p1[1];
  float e2 = bee[2] + p0[2] + p1[2];
  float e3 = bee[3] + p0[3] + p1[3];
  int idx = (m*256+n)*4;
  f32x4 eo; eo[0]=e0; eo[1]=e1; eo[2]=e2; eo[3]=e3;
  *reinterpret_cast<f32x4*>(eeout + idx) = eo;
  int okmn = ok[m] & ok[n];
  f32x4 em;
  em[0] = (okmn && e0 > 0.f) ? e0 : NEGV;
  em[1] = (okmn && e1 > 0.f) ? e1 : NEGV;
  em[2] = (okmn && e2 > 0.f) ? e2 : NEGV;
  em[3] = (okmn && e3 > 0.f) ? e3 : NEGV;
  *reinterpret_cast<f32x4*>(eemask + idx) = em;
  if (em[0] > -1e29f || em[1] > -1e29f || em[2] > -1e29f || em[3] > -1e29f) atomicOr(flag, 1);
}

// ---------------- WeT[it][k][h] = bf16(W_ne[it][512+h][k])  (transpose for MFMA B-frags)
__global__ __launch_bounds__(256) void k_wet(const float* __restrict__ Wne,
                                             __hip_bfloat16* __restrict__ WeT)
{
  int bid = blockIdx.x; int i = bid >> 8, k = bid & 255, h = threadIdx.x;
  WeT[i*65536 + k*256 + h] = __float2bfloat16(Wne[i*197632 + (512+h)*256 + k]);
}

// ---------------- tiled fp32 -> bf16 transpose: out[N][K] = bf16(in[K][N]), 64x64 tiles
__global__ __launch_bounds__(256) void k_transpose_bf16(
  const float* __restrict__ in, __hip_bfloat16* __restrict__ out, int K, int N, int ktiles)
{
  __shared__ float t[64][65];
  int kt = blockIdx.x % ktiles, nt = blockIdx.x / ktiles;
  int k0 = kt*64, n0 = nt*64;
  int tid = threadIdx.x; int c = tid & 63, rg = tid >> 6;
  #pragma unroll
  for (int rr = 0; rr < 16; ++rr){
    int row = rg + rr*4;
    t[row][c] = in[(k0+row)*N + n0 + c];
  }
  __syncthreads();
  #pragma unroll
  for (int rr = 0; rr < 16; ++rr){
    int row = rg + rr*4;
    out[(n0+row)*K + k0 + c] = __float2bfloat16(t[c][row]);
  }
}

// ---------------- WsemT[64][256]: WsemT[c][j] = bf16(Wsem[j][c]) (pad c>=50 with 0)
__global__ __launch_bounds__(256) void k_wsem(const float* __restrict__ Wsem,
                                              __hip_bfloat16* __restrict__ WsemT)
{
  int tid = threadIdx.x;
  int j = blockIdx.x*4 + (tid>>6), c = tid & 63;
  float v = (c < 50) ? Wsem[j*50+c] : 0.f;
  WsemT[c*256 + j] = __float2bfloat16(v);
}

// ---------------- s'[m,k]=cf@Ws + b_ne ; d[n,k]=cf@Wd  (fp32, row-blocked RB=4)
__global__ __launch_bounds__(256) void k_sd(
  const float* __restrict__ cf, const float* __restrict__ Wne,
  const float* __restrict__ bne, float* __restrict__ sp, float* __restrict__ d, int it)
{
  __shared__ float cfs[4][256];
  int bid = blockIdx.x; int sel = bid >> 6; int m0 = (bid & 63)*4; int tid = threadIdx.x;
  #pragma unroll
  for (int r = 0; r < 4; ++r) cfs[r][tid] = cf[(m0+r)*256 + tid];
  __syncthreads();
  const float* W = Wne + it*197632 + sel*65536;
  float bias = sel ? 0.f : bne[it*256+tid];
  float acc0 = bias, acc1 = bias, acc2 = bias, acc3 = bias;
  #pragma unroll 8
  for (int j = 0; j < 256; ++j){
    float w = W[j*256+tid];
    acc0 = fmaf(cfs[0][j], w, acc0);
    acc1 = fmaf(cfs[1][j], w, acc1);
    acc2 = fmaf(cfs[2][j], w, acc2);
    acc3 = fmaf(cfs[3][j], w, acc3);
  }
  float* dst = sel ? d : sp;
  dst[(m0+0)*256+tid] = acc0;
  dst[(m0+1)*256+tid] = acc1;
  dst[(m0+2)*256+tid] = acc2;
  dst[(m0+3)*256+tid] = acc3;
}

// ---------------- fused per-iteration: el recompute -> MFMA E=el@We -> masked max
// grid = m(256) x kc(4). Block owns out[m, kc*64..+64); We^T chunk (64x256 bf16,
// XOR-swizzled) in LDS shared by 4 waves. Wave w covers n in [w*64, w*64+64).
// launch_bounds(256,2): cap 256 VGPR -> ~150-reg working set fits, NO SPILL
// (256,3)/(256,4) forced 84/64 regs and 150-270MB of scratch traffic.
__global__ __launch_bounds__(256,2) void k_fused(
  const float* __restrict__ a, const float* __restrict__ bel,
  const float* __restrict__ b2, const __hip_bfloat16* __restrict__ wet,
  const float* __restrict__ sp, const float* __restrict__ dmat,
  const float* __restrict__ eemask, const float* __restrict__ Wne_it,
  float* __restrict__ cf, __hip_bfloat16* __restrict__ cfcb,
  const int* __restrict__ flag, int it)
{
  __shared__ __attribute__((aligned(16))) char weS[32768]; // [64 k-rows][256 h] bf16, swizzled
  __shared__ float ac[256];
  __shared__ float red[4][64];
  int bid = blockIdx.x; int m = bid >> 2; int kc = bid & 3;
  int tid = threadIdx.x;
  ac[tid] = a[m*256+tid] + bel[tid];
  // stage We^T chunk: 2048 x 16B, swizzle byte ^= (row&7)<<4
  const char* wsrc = reinterpret_cast<const char*>(wet + kc*16384);
  #pragma unroll
  for (int p = 0; p < 8; ++p){
    int i = p*256 + tid;
    int row = i >> 5, colb = (i & 31) << 4;
    int byte = (row << 9) | colb;
    *reinterpret_cast<bf16x8*>(weS + (byte ^ ((row & 7) << 4))) =
      *reinterpret_cast<const bf16x8*>(wsrc + byte);
  }
  __syncthreads();

  int w = tid >> 6, l = tid & 63, l15 = l & 15, lg = l >> 4;
  float spv[4], wtv[4][4];
  #pragma unroll
  for (int kt = 0; kt < 4; ++kt){
    int kcol = kc*64 + kt*16 + l15;
    spv[kt] = sp[m*256+kcol];
    #pragma unroll
    for (int t = 0; t < 4; ++t) wtv[t][kt] = Wne_it[(768+t)*256 + kcol];
  }
  // per-kt LDS read bases (byte): row = kt*16+l15
  int rowb[4], rowx[4];
  #pragma unroll
  for (int kt = 0; kt < 4; ++kt){
    int row = kt*16 + l15;
    rowb[kt] = row << 9;
    rowx[kt] = (row & 7) << 4;
  }
  float runmax[4] = {NEGV, NEGV, NEGV, NEGV};

  for (int ni = 0; ni < 4; ++ni){
    int nb = w*64 + ni*16;
    const float* b2r = b2 + (nb + l15)*256;
    f32x4 acc0 = {0,0,0,0}, acc1 = {0,0,0,0}, acc2 = {0,0,0,0}, acc3 = {0,0,0,0};
    #pragma unroll
    for (int kk = 0; kk < 8; ++kk){
      // transient A-frag: el[nb+l15][kk*32+lg*8 .. +8]
      int h0 = kk*32 + lg*8;
      f32x4 bb0 = *reinterpret_cast<const f32x4*>(b2r + h0);
      f32x4 bb1 = *reinterpret_cast<const f32x4*>(b2r + h0 + 4);
      f32x4 aa0 = *reinterpret_cast<const f32x4*>(ac + h0);
      f32x4 aa1 = *reinterpret_cast<const f32x4*>(ac + h0 + 4);
      union { uint16_t u[8]; bf16x8 v; } fr;
      #pragma unroll
      for (int j = 0; j < 4; ++j){
        fr.u[j]   = f2bfu(fmaxf(aa0[j]+bb0[j], 0.f));
        fr.u[j+4] = f2bfu(fmaxf(aa1[j]+bb1[j], 0.f));
      }
      int c = kk*64 + lg*16;
      bf16x8 B0 = *reinterpret_cast<const bf16x8*>(weS + ((rowb[0] + c) ^ rowx[0]));
      bf16x8 B1 = *reinterpret_cast<const bf16x8*>(weS + ((rowb[1] + c) ^ rowx[1]));
      bf16x8 B2 = *reinterpret_cast<const bf16x8*>(weS + ((rowb[2] + c) ^ rowx[2]));
      bf16x8 B3 = *reinterpret_cast<const bf16x8*>(weS + ((rowb[3] + c) ^ rowx[3]));
      acc0 = __builtin_amdgcn_mfma_f32_16x16x32_bf16(fr.v, B0, acc0, 0, 0, 0);
      acc1 = __builtin_amdgcn_mfma_f32_16x16x32_bf16(fr.v, B1, acc1, 0, 0, 0);
      acc2 = __builtin_amdgcn_mfma_f32_16x16x32_bf16(fr.v, B2, acc2, 0, 0, 0);
      acc3 = __builtin_amdgcn_mfma_f32_16x16x32_bf16(fr.v, B3, acc3, 0, 0, 0);
    }
    // D layout: col = l15 (k_local), row = lg*4 + r (n_local)
    #pragma unroll
    for (int r = 0; r < 4; ++r){
      int n = nb + lg*4 + r;
      f32x4 me = *reinterpret_cast<const f32x4*>(eemask + (m*256+n)*4);
      const float* dr = dmat + n*256 + kc*64;
      float Ed0 = acc0[r] + dr[     l15] + spv[0];
      float Ed1 = acc1[r] + dr[16 + l15] + spv[1];
      float Ed2 = acc2[r] + dr[32 + l15] + spv[2];
      float Ed3 = acc3[r] + dr[48 + l15] + spv[3];
      #pragma unroll
      for (int t = 0; t < 4; ++t){
        if (me[t] > -1e29f){
          runmax[0] = fmaxf(runmax[0], fmaf(me[t], wtv[t][0], Ed0));
          runmax[1] = fmaxf(runmax[1], fmaf(me[t], wtv[t][1], Ed1));
          runmax[2] = fmaxf(runmax[2], fmaf(me[t], wtv[t][2], Ed2));
          runmax[3] = fmaxf(runmax[3], fmaf(me[t], wtv[t][3], Ed3));
        }
      }
    }
  }
  // reduce over lg (n-rows within wave), then across waves via LDS
  #pragma unroll
  for (int kt = 0; kt < 4; ++kt){
    float v = runmax[kt];
    v = fmaxf(v, __shfl_xor(v, 16));
    v = fmaxf(v, __shfl_xor(v, 32));
    if (l < 16) red[w][kt*16 + l] = v;
  }
  __syncthreads();
  if (tid < 64){
    float v = fmaxf(fmaxf(red[0][tid], red[1][tid]), fmaxf(red[2][tid], red[3][tid]));
    float nv = fmaxf(v, 0.f);
    int kcol = kc*64 + tid;
    float outv = (*flag) ? nv : cf[m*256+kcol];
    cf[m*256+kcol] = outv;
    cfcb[m*768 + 256*(it+1) + kcol] = __float2bfloat16(outv);
  }
}

// ---------------- final MFMA: ch = relu(cfc@Wch+b); feats = relu(ch@Wc2+b); sem = ch@Wsem+b
__global__ __launch_bounds__(256) void k_final_mfma(
  const __hip_bfloat16* __restrict__ cfcb, const __hip_bfloat16* __restrict__ WchT,
  const float* __restrict__ bch, const __hip_bfloat16* __restrict__ Wc2T,
  const float* __restrict__ bc2, const __hip_bfloat16* __restrict__ WsemT,
  const float* __restrict__ bsem, float* __restrict__ feats_out,
  float* __restrict__ sem_out)
{
  __shared__ char chs[8192];   // ch tile 16x256 bf16, XOR-swizzled
  int tid = threadIdx.x; int w = tid>>6, l = tid&63, l15 = l&15, lg = l>>4;
  int m0 = blockIdx.x*16;

  // phase 1: ch = relu(cfc @ Wch + bch), K=768
  f32x4 acc[4] = {{0,0,0,0},{0,0,0,0},{0,0,0,0},{0,0,0,0}};
  const __hip_bfloat16* Aptr = cfcb + (m0 + l15)*768;
  #pragma unroll 2
  for (int ks = 0; ks < 24; ++ks){
    int k0 = ks*32 + lg*8;
    bf16x8 Af = *reinterpret_cast<const bf16x8*>(Aptr + k0);
    #pragma unroll
    for (int nt = 0; nt < 4; ++nt){
      int col = w*64 + nt*16 + l15;
      bf16x8 Bf = *reinterpret_cast<const bf16x8*>(WchT + col*768 + k0);
      acc[nt] = __builtin_amdgcn_mfma_f32_16x16x32_bf16(Af, Bf, acc[nt], 0, 0, 0);
    }
  }
  #pragma unroll
  for (int nt = 0; nt < 4; ++nt){
    int col = w*64 + nt*16 + l15;
    float bias = bch[col];
    #pragma unroll
    for (int r = 0; r < 4; ++r){
      int row = lg*4 + r;
      float v = fmaxf(acc[nt][r] + bias, 0.f);
      int byte = ((row*256 + col)*2) ^ ((row&7)<<4);
      *reinterpret_cast<__hip_bfloat16*>(chs + byte) = __float2bfloat16(v);
    }
  }
  __syncthreads();

  // phase 2: feats = relu(ch@Wc2+bc2) [N=256], sem = ch@Wsem+bsem [N=64 padded]
  f32x4 accf[4] = {{0,0,0,0},{0,0,0,0},{0,0,0,0},{0,0,0,0}};
  f32x4 accs = {0,0,0,0};
  int cols_sem = w*16 + l15;
  #pragma unroll 2
  for (int ks = 0; ks < 8; ++ks){
    int k0 = ks*32 + lg*8;
    int byteA = (l15*512 + k0*2) ^ ((l15&7)<<4);
    bf16x8 Af = *reinterpret_cast<const bf16x8*>(chs + byteA);
    #pragma unroll
    for (int nt = 0; nt < 4; ++nt){
      int col = w*64 + nt*16 + l15;
      bf16x8 Bf = *reinterpret_cast<const bf16x8*>(Wc2T + col*256 + k0);
      accf[nt] = __builtin_amdgcn_mfma_f32_16x16x32_bf16(Af, Bf, accf[nt], 0, 0, 0);
    }
    bf16x8 Bs = *reinterpret_cast<const bf16x8*>(WsemT + cols_sem*256 + k0);
    accs = __builtin_amdgcn_mfma_f32_16x16x32_bf16(Af, Bs, accs, 0, 0, 0);
  }
  #pragma unroll
  for (int nt = 0; nt < 4; ++nt){
    int col = w*64 + nt*16 + l15;
    float bias = bc2[col];
    #pragma unroll
    for (int r = 0; r < 4; ++r){
      int row = m0 + lg*4 + r;
      feats_out[row*256 + col] = fmaxf(accf[nt][r] + bias, 0.f);
    }
  }
  if (cols_sem < 50){
    float bias = bsem[cols_sem];
    #pragma unroll
    for (int r = 0; r < 4; ++r){
      int row = m0 + lg*4 + r;
      sem_out[row*50 + cols_sem] = accs[r] + bias;
    }
  }
}

extern "C" void kernel_launch(void* const* d_in, const int* in_sizes, int n_in,
                              void* d_out, int out_size, void* d_ws, size_t ws_size,
                              hipStream_t stream)
{
  const float* pf  = (const float*)d_in[0];
  const float* gc  = (const float*)d_in[1];
  const float* gn  = (const float*)d_in[2];
  const float* Wp  = (const float*)d_in[3];
  const float* bp  = (const float*)d_in[4];
  const float* Wex = (const float*)d_in[5];
  const float* bex = (const float*)d_in[6];
  const float* Wsem= (const float*)d_in[7];
  const float* bsem= (const float*)d_in[8];
  const float* Wel = (const float*)d_in[9];
  const float* bel = (const float*)d_in[10];
  const float* Wee = (const float*)d_in[11];
  const float* bee = (const float*)d_in[12];
  const float* Wne = (const float*)d_in[13];
  const float* bne = (const float*)d_in[14];
  const float* Wch = (const float*)d_in[15];
  const float* bch = (const float*)d_in[16];
  const float* Wc2 = (const float*)d_in[17];
  const float* bc2 = (const float*)d_in[18];

  float* out = (float*)d_out;
  float* feats_out = out;             // 65536
  float* sem_out   = out + 65536;     // 12800
  float* ex_out    = out + 78336;     // 256
  float* ee_out    = out + 78592;     // 262144

  char* ws = (char*)d_ws;
  float* cf    = (float*)(ws);                       // 256 KB
  float* a_    = (float*)(ws + ( 256u<<10));         // 256 KB
  float* b2_   = (float*)(ws + ( 512u<<10));         // 256 KB
  float* b2T   = (float*)(ws + ( 768u<<10));         // 256 KB
  float* sp_   = (float*)(ws + (1024u<<10));         // 256 KB
  float* dmat  = (float*)(ws + (1280u<<10));         // 256 KB
  float* eem   = (float*)(ws + (1536u<<10));         // 1 MB
  __hip_bfloat16* WeT   = (__hip_bfloat16*)(ws + (2560u<<10)); // 256 KB
  __hip_bfloat16* cfcb  = (__hip_bfloat16*)(ws + (2816u<<10)); // 384 KB
  __hip_bfloat16* WchT  = (__hip_bfloat16*)(ws + (3200u<<10)); // 384 KB
  __hip_bfloat16* Wc2T  = (__hip_bfloat16*)(ws + (3584u<<10)); // 128 KB
  __hip_bfloat16* WsemT = (__hip_bfloat16*)(ws + (3712u<<10)); //  32 KB
  int* ok   = (int*)(ws + (3744u<<10));
  int* flag = ok + 256;
  // time-shared 2MB window: pchild (k_child), pee (k_ee)
  float* pchild = (float*)(ws + (3776u<<10));        // 2 MB
  float* pee    = pchild;                            // 2 MB

  k_child_part<<<512,256,0,stream>>>(pf,gc,gn,Wp,pchild);
  k_child_reduce<<<256,256,0,stream>>>(pchild,bp,cf,cfcb);

  // weight preps (after pchild consumed)
  k_wet<<<512,256,0,stream>>>(Wne,WeT);
  k_transpose_bf16<<<48,256,0,stream>>>(Wch, WchT, 768, 256, 12);
  k_transpose_bf16<<<16,256,0,stream>>>(Wc2, Wc2T, 256, 256, 4);
  k_wsem<<<64,256,0,stream>>>(Wsem, WsemT);

  k_exists<<<256,256,0,stream>>>(cf,Wex,bex,ex_out,ok,flag);
  k_ab<<<128,256,0,stream>>>(cf,Wel,a_,b2_,b2T);
  k_ee_part<<<512,256,0,stream>>>(a_,b2T,bel,Wee,pee);
  k_ee_combine<<<256,256,0,stream>>>(pee,bee,ok,eem,ee_out,flag);
  for (int it = 0; it < 2; ++it){
    k_sd<<<128,256,0,stream>>>(cf,Wne,bne,sp_,dmat,it);
    k_fused<<<1024,256,0,stream>>>(a_,bel,b2_,WeT + it*65536,sp_,dmat,eem,
                                   Wne + it*197632,cf,cfcb,flag,it);
  }
  k_final_mfma<<<16,256,0,stream>>>(cfcb,WchT,bch,Wc2T,bc2,WsemT,bsem,feats_out,sem_out);
}

// Round 8
// 171.297 us; speedup vs baseline: 2.0345x; 1.1740x over previous
//
#include <hip/hip_runtime.h>
#include <hip/hip_bf16.h>
#include <stdint.h>

#define NEGV -1e30f

typedef __attribute__((ext_vector_type(8))) __bf16 bf16x8;
typedef __attribute__((ext_vector_type(4))) float f32x4;

__device__ __forceinline__ uint16_t f2bfu(float f){
  __hip_bfloat16 h = __float2bfloat16(f);
  return *reinterpret_cast<const uint16_t*>(&h);
}

// ---------------- child part: K-split matvec partials. grid = 64 jb x 8 ks
__global__ __launch_bounds__(256) void k_child_part(
    const float* __restrict__ pf, const float* __restrict__ gc,
    const float* __restrict__ gn, const float* __restrict__ Wp,
    float* __restrict__ pchild)
{
  __shared__ float xs[36];
  int jb = blockIdx.x & 63, ks = blockIdx.x >> 6;
  int tid = threadIdx.x;
  int i0 = ks*36, i1 = (i0+36 < 282) ? i0+36 : 282;
  if (tid < i1-i0){
    int i = i0 + tid;
    xs[tid] = (i < 256) ? pf[i] : ((i < 272) ? gc[i-256] : gn[i-272]);
  }
  __syncthreads();
  int j0 = jb*1024 + tid*4;
  f32x4 acc = {0,0,0,0};
  #pragma unroll 6
  for (int i = i0; i < i1; ++i){
    f32x4 w = *reinterpret_cast<const f32x4*>(Wp + i*65536 + j0);
    float x = xs[i-i0];
    acc[0] = fmaf(x, w[0], acc[0]);
    acc[1] = fmaf(x, w[1], acc[1]);
    acc[2] = fmaf(x, w[2], acc[2]);
    acc[3] = fmaf(x, w[3], acc[3]);
  }
  *reinterpret_cast<f32x4*>(pchild + ks*65536 + j0) = acc;
}

// ---------------- child reduce: sum partials + bias + relu -> cf, cfcb slot 0
__global__ __launch_bounds__(256) void k_child_reduce(
  const float* __restrict__ pchild, const float* __restrict__ bp,
  float* __restrict__ cf, __hip_bfloat16* __restrict__ cfcb)
{
  int j = blockIdx.x*256 + threadIdx.x;
  float s = bp[j];
  #pragma unroll
  for (int ks = 0; ks < 8; ++ks) s += pchild[ks*65536 + j];
  s = fmaxf(s, 0.f);
  cf[j] = s;
  cfcb[(j>>8)*768 + (j&255)] = __float2bfloat16(s);
}

// ---------------- exists logits + node_ok + zero has_edges flag
__global__ __launch_bounds__(256) void k_exists(
  const float* __restrict__ cf, const float* __restrict__ Wex,
  const float* __restrict__ bex, float* __restrict__ exout,
  int* __restrict__ ok, int* __restrict__ flag)
{
  __shared__ float red[256];
  int m = blockIdx.x, tid = threadIdx.x;
  red[tid] = cf[m*256+tid]*Wex[tid];
  __syncthreads();
  for (int s = 128; s > 0; s >>= 1){ if (tid < s) red[tid] += red[tid+s]; __syncthreads(); }
  if (tid == 0){
    float logit = red[0] + bex[0];
    exout[m] = logit;
    ok[m] = logit > 0.f ? 1 : 0;
    if (m == 0) *flag = 0;
  }
}

// ---------------- a = cf@W_el[:H], b2 = cf@W_el[H:]  (fp32, row-blocked RB=4; also writes b2T)
__global__ __launch_bounds__(256) void k_ab(
  const float* __restrict__ cf, const float* __restrict__ Wel,
  float* __restrict__ a, float* __restrict__ b2, float* __restrict__ b2T)
{
  __shared__ float cfs[4][256];
  int bid = blockIdx.x; int sel = bid >> 6; int m0 = (bid & 63)*4; int tid = threadIdx.x;
  #pragma unroll
  for (int r = 0; r < 4; ++r) cfs[r][tid] = cf[(m0+r)*256 + tid];
  __syncthreads();
  const float* W = Wel + sel*65536;
  float acc0 = 0.f, acc1 = 0.f, acc2 = 0.f, acc3 = 0.f;
  #pragma unroll 8
  for (int j = 0; j < 256; ++j){
    float w = W[j*256+tid];
    acc0 = fmaf(cfs[0][j], w, acc0);
    acc1 = fmaf(cfs[1][j], w, acc1);
    acc2 = fmaf(cfs[2][j], w, acc2);
    acc3 = fmaf(cfs[3][j], w, acc3);
  }
  float* dst = sel ? b2 : a;
  dst[(m0+0)*256+tid] = acc0;
  dst[(m0+1)*256+tid] = acc1;
  dst[(m0+2)*256+tid] = acc2;
  dst[(m0+3)*256+tid] = acc3;
  if (sel){
    b2T[tid*256 + m0+0] = acc0;
    b2T[tid*256 + m0+1] = acc1;
    b2T[tid*256 + m0+2] = acc2;
    b2T[tid*256 + m0+3] = acc3;
  }
}

// ---------------- el pack: el[m,n,h]=relu(a[m,h]+b2[n,h]+bel[h]) -> bf16 MFMA A-frags
// grid = m(256) x nt(4); frag layout: elp[((T*8+kk)*64 + lane)*16B], T = m*16 + nt*4 + w
__global__ __launch_bounds__(256) void k_elpack(
  const float* __restrict__ a, const float* __restrict__ b2,
  const float* __restrict__ bel, __hip_bfloat16* __restrict__ elp)
{
  __shared__ float b2s[64*260];   // 64 rows, stride 260 (pad 4) -> 2-way banks max
  __shared__ float acs[256];
  int bid = blockIdx.x; int m = bid >> 2, nt = bid & 3;
  int tid = threadIdx.x;
  acs[tid] = a[m*256+tid] + bel[tid];
  const float* src = b2 + nt*64*256;
  #pragma unroll
  for (int p = 0; p < 16; ++p){
    int i4 = p*256 + tid;                 // f32x4 index, 4096 total
    int row = i4 >> 6, c4 = (i4 & 63) << 2;
    *reinterpret_cast<f32x4*>(&b2s[row*260 + c4]) =
      *reinterpret_cast<const f32x4*>(src + i4*4);
  }
  __syncthreads();
  int w = tid>>6, l = tid&63, l15 = l&15, lg = l>>4;
  int T = m*16 + nt*4 + w;
  const float* br = &b2s[(w*16+l15)*260];
  char* outb = reinterpret_cast<char*>(elp) + (size_t)T*8192 + (size_t)l*16;
  #pragma unroll
  for (int kk = 0; kk < 8; ++kk){
    int h0 = kk*32 + lg*8;
    f32x4 bb0 = *reinterpret_cast<const f32x4*>(br + h0);
    f32x4 bb1 = *reinterpret_cast<const f32x4*>(br + h0 + 4);
    f32x4 aa0 = *reinterpret_cast<const f32x4*>(acs + h0);
    f32x4 aa1 = *reinterpret_cast<const f32x4*>(acs + h0 + 4);
    union { uint16_t u[8]; bf16x8 v; } fr;
    #pragma unroll
    for (int j = 0; j < 4; ++j){
      fr.u[j]   = f2bfu(fmaxf(aa0[j]+bb0[j], 0.f));
      fr.u[j+4] = f2bfu(fmaxf(aa1[j]+bb1[j], 0.f));
    }
    *reinterpret_cast<bf16x8*>(outb + kk*1024) = fr.v;
  }
}

// ---------------- ee part: h-split 2. grid = m(256) x hs(2); partial e[4] per (m,n)
__global__ __launch_bounds__(256) void k_ee_part(
  const float* __restrict__ a, const float* __restrict__ b2T,
  const float* __restrict__ bel, const float* __restrict__ Wee,
  float* __restrict__ pee)
{
  __shared__ float wee[4][128];
  __shared__ float ac[128];
  int bid = blockIdx.x; int m = bid & 255; int hs = bid >> 8;
  int tid = threadIdx.x;
  int h0 = hs*128;
  if (tid < 128){
    ac[tid] = a[m*256 + h0 + tid] + bel[h0 + tid];
    wee[0][tid] = Wee[      h0 + tid];
    wee[1][tid] = Wee[256 + h0 + tid];
  } else {
    int t = tid - 128;
    wee[2][t] = Wee[512 + h0 + t];
    wee[3][t] = Wee[768 + h0 + t];
  }
  __syncthreads();
  int n = tid;
  float e0 = 0.f, e1 = 0.f, e2 = 0.f, e3 = 0.f;
  #pragma unroll 8
  for (int h = 0; h < 128; ++h){
    float el = fmaxf(ac[h] + b2T[(h0+h)*256 + n], 0.f);
    e0 = fmaf(el, wee[0][h], e0);
    e1 = fmaf(el, wee[1][h], e1);
    e2 = fmaf(el, wee[2][h], e2);
    e3 = fmaf(el, wee[3][h], e3);
  }
  f32x4 p; p[0]=e0; p[1]=e1; p[2]=e2; p[3]=e3;
  *reinterpret_cast<f32x4*>(pee + ((hs*256+m)*256 + n)*4) = p;
}

// ---------------- ee combine: bias + partials -> eeout, eemask, flag
__global__ __launch_bounds__(256) void k_ee_combine(
  const float* __restrict__ pee, const float* __restrict__ bee,
  const int* __restrict__ ok, float* __restrict__ eemask,
  float* __restrict__ eeout, int* __restrict__ flag)
{
  int m = blockIdx.x, n = threadIdx.x;
  f32x4 p0 = *reinterpret_cast<const f32x4*>(pee + ((0*256+m)*256 + n)*4);
  f32x4 p1 = *reinterpret_cast<const f32x4*>(pee + ((1*256+m)*256 + n)*4);
  float e0 = bee[0] + p0[0] + p1[0];
  float e1 = bee[1] + p0[1] + p1[1];
  float e2 = bee[2] + p0[2] + p1[2];
  float e3 = bee[3] + p0[3] + p1[3];
  int idx = (m*256+n)*4;
  f32x4 eo; eo[0]=e0; eo[1]=e1; eo[2]=e2; eo[3]=e3;
  *reinterpret_cast<f32x4*>(eeout + idx) = eo;
  int okmn = ok[m] & ok[n];
  f32x4 em;
  em[0] = (okmn && e0 > 0.f) ? e0 : NEGV;
  em[1] = (okmn && e1 > 0.f) ? e1 : NEGV;
  em[2] = (okmn && e2 > 0.f) ? e2 : NEGV;
  em[3] = (okmn && e3 > 0.f) ? e3 : NEGV;
  *reinterpret_cast<f32x4*>(eemask + idx) = em;
  if (em[0] > -1e29f || em[1] > -1e29f || em[2] > -1e29f || em[3] > -1e29f) atomicOr(flag, 1);
}

// ---------------- tiled fp32 -> bf16 transpose: out[N][K] = bf16(in[K][N]), 64x64 tiles
__global__ __launch_bounds__(256) void k_transpose_bf16(
  const float* __restrict__ in, __hip_bfloat16* __restrict__ out, int K, int N, int ktiles)
{
  __shared__ float t[64][65];
  int kt = blockIdx.x % ktiles, nt = blockIdx.x / ktiles;
  int k0 = kt*64, n0 = nt*64;
  int tid = threadIdx.x; int c = tid & 63, rg = tid >> 6;
  #pragma unroll
  for (int rr = 0; rr < 16; ++rr){
    int row = rg + rr*4;
    t[row][c] = in[(k0+row)*N + n0 + c];
  }
  __syncthreads();
  #pragma unroll
  for (int rr = 0; rr < 16; ++rr){
    int row = rg + rr*4;
    out[(n0+row)*K + k0 + c] = __float2bfloat16(t[c][row]);
  }
}

// ---------------- WsemT[64][256]: WsemT[c][j] = bf16(Wsem[j][c]) (pad c>=50 with 0)
__global__ __launch_bounds__(256) void k_wsem(const float* __restrict__ Wsem,
                                              __hip_bfloat16* __restrict__ WsemT)
{
  int tid = threadIdx.x;
  int j = blockIdx.x*4 + (tid>>6), c = tid & 63;
  float v = (c < 50) ? Wsem[j*50+c] : 0.f;
  WsemT[c*256 + j] = __float2bfloat16(v);
}

// ---------------- s'[m,k]=cf@Ws + b_ne ; d[n,k]=cf@Wd  (fp32, row-blocked RB=4)
__global__ __launch_bounds__(256) void k_sd(
  const float* __restrict__ cf, const float* __restrict__ Wne,
  const float* __restrict__ bne, float* __restrict__ sp, float* __restrict__ d, int it)
{
  __shared__ float cfs[4][256];
  int bid = blockIdx.x; int sel = bid >> 6; int m0 = (bid & 63)*4; int tid = threadIdx.x;
  #pragma unroll
  for (int r = 0; r < 4; ++r) cfs[r][tid] = cf[(m0+r)*256 + tid];
  __syncthreads();
  const float* W = Wne + it*197632 + sel*65536;
  float bias = sel ? 0.f : bne[it*256+tid];
  float acc0 = bias, acc1 = bias, acc2 = bias, acc3 = bias;
  #pragma unroll 8
  for (int j = 0; j < 256; ++j){
    float w = W[j*256+tid];
    acc0 = fmaf(cfs[0][j], w, acc0);
    acc1 = fmaf(cfs[1][j], w, acc1);
    acc2 = fmaf(cfs[2][j], w, acc2);
    acc3 = fmaf(cfs[3][j], w, acc3);
  }
  float* dst = sel ? d : sp;
  dst[(m0+0)*256+tid] = acc0;
  dst[(m0+1)*256+tid] = acc1;
  dst[(m0+2)*256+tid] = acc2;
  dst[(m0+3)*256+tid] = acc3;
}

// ---------------- fused (elp path): coalesced A-frag loads + LDS B + reg-prefetched epilogue
__global__ __launch_bounds__(256,2) void k_fused_elp(
  const __hip_bfloat16* __restrict__ elp, const __hip_bfloat16* __restrict__ wet,
  const float* __restrict__ sp, const float* __restrict__ dmat,
  const float* __restrict__ eemask, const float* __restrict__ Wne_it,
  float* __restrict__ cf, __hip_bfloat16* __restrict__ cfcb,
  const int* __restrict__ flag, int it)
{
  __shared__ __attribute__((aligned(16))) char weS[32768];
  __shared__ float red[4][64];
  int bid = blockIdx.x; int m = bid >> 2, kc = bid & 3;
  int tid = threadIdx.x;
  const char* wsrc = reinterpret_cast<const char*>(wet + kc*16384);
  #pragma unroll
  for (int p = 0; p < 8; ++p){
    int i = p*256 + tid;
    int row = i >> 5, colb = (i & 31) << 4;
    int byte = (row << 9) | colb;
    *reinterpret_cast<bf16x8*>(weS + (byte ^ ((row & 7) << 4))) =
      *reinterpret_cast<const bf16x8*>(wsrc + byte);
  }
  __syncthreads();

  int w = tid >> 6, l = tid & 63, l15 = l & 15, lg = l >> 4;
  float spv[4], wtv[4][4];
  #pragma unroll
  for (int kt = 0; kt < 4; ++kt){
    int kcol = kc*64 + kt*16 + l15;
    spv[kt] = sp[m*256+kcol];
    #pragma unroll
    for (int t = 0; t < 4; ++t) wtv[t][kt] = Wne_it[(768+t)*256 + kcol];
  }
  int rowb[4], rowx[4];
  #pragma unroll
  for (int kt = 0; kt < 4; ++kt){
    int row = kt*16 + l15;
    rowb[kt] = row << 9;
    rowx[kt] = (row & 7) << 4;
  }
  float runmax[4] = {NEGV, NEGV, NEGV, NEGV};

  for (int ni = 0; ni < 4; ++ni){
    int nb = w*64 + ni*16;
    int T = m*16 + w*4 + ni;
    const char* ap = reinterpret_cast<const char*>(elp) + (size_t)T*8192 + (size_t)l*16;
    // prefetch epilogue operands (me + d) into regs — independent of MFMA chain
    f32x4 me[4];
    float dv[4][4];
    #pragma unroll
    for (int r = 0; r < 4; ++r){
      int n = nb + lg*4 + r;
      me[r] = *reinterpret_cast<const f32x4*>(eemask + (m*256+n)*4);
      const float* dr = dmat + n*256 + kc*64;
      #pragma unroll
      for (int kt = 0; kt < 4; ++kt) dv[r][kt] = dr[kt*16 + l15];
    }
    // A-frags: coalesced 16B/lane loads
    bf16x8 Af[8];
    #pragma unroll
    for (int kk = 0; kk < 8; ++kk)
      Af[kk] = *reinterpret_cast<const bf16x8*>(ap + kk*1024);

    f32x4 acc0 = {0,0,0,0}, acc1 = {0,0,0,0}, acc2 = {0,0,0,0}, acc3 = {0,0,0,0};
    #pragma unroll
    for (int kk = 0; kk < 8; ++kk){
      int c = kk*64 + lg*16;
      bf16x8 B0 = *reinterpret_cast<const bf16x8*>(weS + ((rowb[0] + c) ^ rowx[0]));
      bf16x8 B1 = *reinterpret_cast<const bf16x8*>(weS + ((rowb[1] + c) ^ rowx[1]));
      bf16x8 B2 = *reinterpret_cast<const bf16x8*>(weS + ((rowb[2] + c) ^ rowx[2]));
      bf16x8 B3 = *reinterpret_cast<const bf16x8*>(weS + ((rowb[3] + c) ^ rowx[3]));
      acc0 = __builtin_amdgcn_mfma_f32_16x16x32_bf16(Af[kk], B0, acc0, 0, 0, 0);
      acc1 = __builtin_amdgcn_mfma_f32_16x16x32_bf16(Af[kk], B1, acc1, 0, 0, 0);
      acc2 = __builtin_amdgcn_mfma_f32_16x16x32_bf16(Af[kk], B2, acc2, 0, 0, 0);
      acc3 = __builtin_amdgcn_mfma_f32_16x16x32_bf16(Af[kk], B3, acc3, 0, 0, 0);
    }
    #pragma unroll
    for (int r = 0; r < 4; ++r){
      float Ed0 = acc0[r] + dv[r][0] + spv[0];
      float Ed1 = acc1[r] + dv[r][1] + spv[1];
      float Ed2 = acc2[r] + dv[r][2] + spv[2];
      float Ed3 = acc3[r] + dv[r][3] + spv[3];
      #pragma unroll
      for (int t = 0; t < 4; ++t){
        if (me[r][t] > -1e29f){
          runmax[0] = fmaxf(runmax[0], fmaf(me[r][t], wtv[t][0], Ed0));
          runmax[1] = fmaxf(runmax[1], fmaf(me[r][t], wtv[t][1], Ed1));
          runmax[2] = fmaxf(runmax[2], fmaf(me[r][t], wtv[t][2], Ed2));
          runmax[3] = fmaxf(runmax[3], fmaf(me[r][t], wtv[t][3], Ed3));
        }
      }
    }
  }
  #pragma unroll
  for (int kt = 0; kt < 4; ++kt){
    float v = runmax[kt];
    v = fmaxf(v, __shfl_xor(v, 16));
    v = fmaxf(v, __shfl_xor(v, 32));
    if (l < 16) red[w][kt*16 + l] = v;
  }
  __syncthreads();
  if (tid < 64){
    float v = fmaxf(fmaxf(red[0][tid], red[1][tid]), fmaxf(red[2][tid], red[3][tid]));
    float nv = fmaxf(v, 0.f);
    int kcol = kc*64 + tid;
    float outv = (*flag) ? nv : cf[m*256+kcol];
    cf[m*256+kcol] = outv;
    cfcb[m*768 + 256*(it+1) + kcol] = __float2bfloat16(outv);
  }
}

// ---------------- fused (fallback, ws too small): round-7 recompute version
__global__ __launch_bounds__(256,2) void k_fused_rec(
  const float* __restrict__ a, const float* __restrict__ bel,
  const float* __restrict__ b2, const __hip_bfloat16* __restrict__ wet,
  const float* __restrict__ sp, const float* __restrict__ dmat,
  const float* __restrict__ eemask, const float* __restrict__ Wne_it,
  float* __restrict__ cf, __hip_bfloat16* __restrict__ cfcb,
  const int* __restrict__ flag, int it)
{
  __shared__ __attribute__((aligned(16))) char weS[32768];
  __shared__ float ac[256];
  __shared__ float red[4][64];
  int bid = blockIdx.x; int m = bid >> 2; int kc = bid & 3;
  int tid = threadIdx.x;
  ac[tid] = a[m*256+tid] + bel[tid];
  const char* wsrc = reinterpret_cast<const char*>(wet + kc*16384);
  #pragma unroll
  for (int p = 0; p < 8; ++p){
    int i = p*256 + tid;
    int row = i >> 5, colb = (i & 31) << 4;
    int byte = (row << 9) | colb;
    *reinterpret_cast<bf16x8*>(weS + (byte ^ ((row & 7) << 4))) =
      *reinterpret_cast<const bf16x8*>(wsrc + byte);
  }
  __syncthreads();
  int w = tid >> 6, l = tid & 63, l15 = l & 15, lg = l >> 4;
  float spv[4], wtv[4][4];
  #pragma unroll
  for (int kt = 0; kt < 4; ++kt){
    int kcol = kc*64 + kt*16 + l15;
    spv[kt] = sp[m*256+kcol];
    #pragma unroll
    for (int t = 0; t < 4; ++t) wtv[t][kt] = Wne_it[(768+t)*256 + kcol];
  }
  int rowb[4], rowx[4];
  #pragma unroll
  for (int kt = 0; kt < 4; ++kt){
    int row = kt*16 + l15;
    rowb[kt] = row << 9;
    rowx[kt] = (row & 7) << 4;
  }
  float runmax[4] = {NEGV, NEGV, NEGV, NEGV};
  for (int ni = 0; ni < 4; ++ni){
    int nb = w*64 + ni*16;
    const float* b2r = b2 + (nb + l15)*256;
    f32x4 acc0 = {0,0,0,0}, acc1 = {0,0,0,0}, acc2 = {0,0,0,0}, acc3 = {0,0,0,0};
    #pragma unroll
    for (int kk = 0; kk < 8; ++kk){
      int h0 = kk*32 + lg*8;
      f32x4 bb0 = *reinterpret_cast<const f32x4*>(b2r + h0);
      f32x4 bb1 = *reinterpret_cast<const f32x4*>(b2r + h0 + 4);
      f32x4 aa0 = *reinterpret_cast<const f32x4*>(ac + h0);
      f32x4 aa1 = *reinterpret_cast<const f32x4*>(ac + h0 + 4);
      union { uint16_t u[8]; bf16x8 v; } fr;
      #pragma unroll
      for (int j = 0; j < 4; ++j){
        fr.u[j]   = f2bfu(fmaxf(aa0[j]+bb0[j], 0.f));
        fr.u[j+4] = f2bfu(fmaxf(aa1[j]+bb1[j], 0.f));
      }
      int c = kk*64 + lg*16;
      bf16x8 B0 = *reinterpret_cast<const bf16x8*>(weS + ((rowb[0] + c) ^ rowx[0]));
      bf16x8 B1 = *reinterpret_cast<const bf16x8*>(weS + ((rowb[1] + c) ^ rowx[1]));
      bf16x8 B2 = *reinterpret_cast<const bf16x8*>(weS + ((rowb[2] + c) ^ rowx[2]));
      bf16x8 B3 = *reinterpret_cast<const bf16x8*>(weS + ((rowb[3] + c) ^ rowx[3]));
      acc0 = __builtin_amdgcn_mfma_f32_16x16x32_bf16(fr.v, B0, acc0, 0, 0, 0);
      acc1 = __builtin_amdgcn_mfma_f32_16x16x32_bf16(fr.v, B1, acc1, 0, 0, 0);
      acc2 = __builtin_amdgcn_mfma_f32_16x16x32_bf16(fr.v, B2, acc2, 0, 0, 0);
      acc3 = __builtin_amdgcn_mfma_f32_16x16x32_bf16(fr.v, B3, acc3, 0, 0, 0);
    }
    #pragma unroll
    for (int r = 0; r < 4; ++r){
      int n = nb + lg*4 + r;
      f32x4 me = *reinterpret_cast<const f32x4*>(eemask + (m*256+n)*4);
      const float* dr = dmat + n*256 + kc*64;
      float Ed0 = acc0[r] + dr[     l15] + spv[0];
      float Ed1 = acc1[r] + dr[16 + l15] + spv[1];
      float Ed2 = acc2[r] + dr[32 + l15] + spv[2];
      float Ed3 = acc3[r] + dr[48 + l15] + spv[3];
      #pragma unroll
      for (int t = 0; t < 4; ++t){
        if (me[t] > -1e29f){
          runmax[0] = fmaxf(runmax[0], fmaf(me[t], wtv[t][0], Ed0));
          runmax[1] = fmaxf(runmax[1], fmaf(me[t], wtv[t][1], Ed1));
          runmax[2] = fmaxf(runmax[2], fmaf(me[t], wtv[t][2], Ed2));
          runmax[3] = fmaxf(runmax[3], fmaf(me[t], wtv[t][3], Ed3));
        }
      }
    }
  }
  #pragma unroll
  for (int kt = 0; kt < 4; ++kt){
    float v = runmax[kt];
    v = fmaxf(v, __shfl_xor(v, 16));
    v = fmaxf(v, __shfl_xor(v, 32));
    if (l < 16) red[w][kt*16 + l] = v;
  }
  __syncthreads();
  if (tid < 64){
    float v = fmaxf(fmaxf(red[0][tid], red[1][tid]), fmaxf(red[2][tid], red[3][tid]));
    float nv = fmaxf(v, 0.f);
    int kcol = kc*64 + tid;
    float outv = (*flag) ? nv : cf[m*256+kcol];
    cf[m*256+kcol] = outv;
    cfcb[m*768 + 256*(it+1) + kcol] = __float2bfloat16(outv);
  }
}

// ---------------- final MFMA: ch = relu(cfc@Wch+b); feats = relu(ch@Wc2+b); sem = ch@Wsem+b
__global__ __launch_bounds__(256) void k_final_mfma(
  const __hip_bfloat16* __restrict__ cfcb, const __hip_bfloat16* __restrict__ WchT,
  const float* __restrict__ bch, const __hip_bfloat16* __restrict__ Wc2T,
  const float* __restrict__ bc2, const __hip_bfloat16* __restrict__ WsemT,
  const float* __restrict__ bsem, float* __restrict__ feats_out,
  float* __restrict__ sem_out)
{
  __shared__ char chs[8192];
  int tid = threadIdx.x; int w = tid>>6, l = tid&63, l15 = l&15, lg = l>>4;
  int m0 = blockIdx.x*16;

  f32x4 acc[4] = {{0,0,0,0},{0,0,0,0},{0,0,0,0},{0,0,0,0}};
  const __hip_bfloat16* Aptr = cfcb + (m0 + l15)*768;
  #pragma unroll 2
  for (int ks = 0; ks < 24; ++ks){
    int k0 = ks*32 + lg*8;
    bf16x8 Af = *reinterpret_cast<const bf16x8*>(Aptr + k0);
    #pragma unroll
    for (int nt = 0; nt < 4; ++nt){
      int col = w*64 + nt*16 + l15;
      bf16x8 Bf = *reinterpret_cast<const bf16x8*>(WchT + col*768 + k0);
      acc[nt] = __builtin_amdgcn_mfma_f32_16x16x32_bf16(Af, Bf, acc[nt], 0, 0, 0);
    }
  }
  #pragma unroll
  for (int nt = 0; nt < 4; ++nt){
    int col = w*64 + nt*16 + l15;
    float bias = bch[col];
    #pragma unroll
    for (int r = 0; r < 4; ++r){
      int row = lg*4 + r;
      float v = fmaxf(acc[nt][r] + bias, 0.f);
      int byte = ((row*256 + col)*2) ^ ((row&7)<<4);
      *reinterpret_cast<__hip_bfloat16*>(chs + byte) = __float2bfloat16(v);
    }
  }
  __syncthreads();

  f32x4 accf[4] = {{0,0,0,0},{0,0,0,0},{0,0,0,0},{0,0,0,0}};
  f32x4 accs = {0,0,0,0};
  int cols_sem = w*16 + l15;
  #pragma unroll 2
  for (int ks = 0; ks < 8; ++ks){
    int k0 = ks*32 + lg*8;
    int byteA = (l15*512 + k0*2) ^ ((l15&7)<<4);
    bf16x8 Af = *reinterpret_cast<const bf16x8*>(chs + byteA);
    #pragma unroll
    for (int nt = 0; nt < 4; ++nt){
      int col = w*64 + nt*16 + l15;
      bf16x8 Bf = *reinterpret_cast<const bf16x8*>(Wc2T + col*256 + k0);
      accf[nt] = __builtin_amdgcn_mfma_f32_16x16x32_bf16(Af, Bf, accf[nt], 0, 0, 0);
    }
    bf16x8 Bs = *reinterpret_cast<const bf16x8*>(WsemT + cols_sem*256 + k0);
    accs = __builtin_amdgcn_mfma_f32_16x16x32_bf16(Af, Bs, accs, 0, 0, 0);
  }
  #pragma unroll
  for (int nt = 0; nt < 4; ++nt){
    int col = w*64 + nt*16 + l15;
    float bias = bc2[col];
    #pragma unroll
    for (int r = 0; r < 4; ++r){
      int row = m0 + lg*4 + r;
      feats_out[row*256 + col] = fmaxf(accf[nt][r] + bias, 0.f);
    }
  }
  if (cols_sem < 50){
    float bias = bsem[cols_sem];
    #pragma unroll
    for (int r = 0; r < 4; ++r){
      int row = m0 + lg*4 + r;
      sem_out[row*50 + cols_sem] = accs[r] + bias;
    }
  }
}

extern "C" void kernel_launch(void* const* d_in, const int* in_sizes, int n_in,
                              void* d_out, int out_size, void* d_ws, size_t ws_size,
                              hipStream_t stream)
{
  const float* pf  = (const float*)d_in[0];
  const float* gc  = (const float*)d_in[1];
  const float* gn  = (const float*)d_in[2];
  const float* Wp  = (const float*)d_in[3];
  const float* bp  = (const float*)d_in[4];
  const float* Wex = (const float*)d_in[5];
  const float* bex = (const float*)d_in[6];
  const float* Wsem= (const float*)d_in[7];
  const float* bsem= (const float*)d_in[8];
  const float* Wel = (const float*)d_in[9];
  const float* bel = (const float*)d_in[10];
  const float* Wee = (const float*)d_in[11];
  const float* bee = (const float*)d_in[12];
  const float* Wne = (const float*)d_in[13];
  const float* bne = (const float*)d_in[14];
  const float* Wch = (const float*)d_in[15];
  const float* bch = (const float*)d_in[16];
  const float* Wc2 = (const float*)d_in[17];
  const float* bc2 = (const float*)d_in[18];

  float* out = (float*)d_out;
  float* feats_out = out;             // 65536
  float* sem_out   = out + 65536;     // 12800
  float* ex_out    = out + 78336;     // 256
  float* ee_out    = out + 78592;     // 262144

  char* ws = (char*)d_ws;
  float* cf    = (float*)(ws);                       // 256 KB
  float* a_    = (float*)(ws + ( 256u<<10));         // 256 KB
  float* b2_   = (float*)(ws + ( 512u<<10));         // 256 KB
  float* b2T   = (float*)(ws + ( 768u<<10));         // 256 KB
  float* sp_   = (float*)(ws + (1024u<<10));         // 256 KB
  float* dmat  = (float*)(ws + (1280u<<10));         // 256 KB
  float* eem   = (float*)(ws + (1536u<<10));         // 1 MB
  __hip_bfloat16* WeT   = (__hip_bfloat16*)(ws + (2560u<<10)); // 256 KB
  __hip_bfloat16* cfcb  = (__hip_bfloat16*)(ws + (2816u<<10)); // 384 KB
  __hip_bfloat16* WchT  = (__hip_bfloat16*)(ws + (3200u<<10)); // 384 KB
  __hip_bfloat16* Wc2T  = (__hip_bfloat16*)(ws + (3584u<<10)); // 128 KB
  __hip_bfloat16* WsemT = (__hip_bfloat16*)(ws + (3712u<<10)); //  32 KB
  int* ok   = (int*)(ws + (3744u<<10));
  int* flag = ok + 256;
  float* pchild = (float*)(ws + (3776u<<10));        // 2 MB (time-shared with pee)
  float* pee    = pchild;
  __hip_bfloat16* elp = (__hip_bfloat16*)(ws + (6144u<<10)); // 33.5 MB packed el frags

  bool use_elp = ws_size >= (41ull << 20);

  k_child_part<<<512,256,0,stream>>>(pf,gc,gn,Wp,pchild);
  k_child_reduce<<<256,256,0,stream>>>(pchild,bp,cf,cfcb);

  // weight preps: WeT via coalesced LDS transpose (2 its), Wch/Wc2/Wsem
  for (int it = 0; it < 2; ++it)
    k_transpose_bf16<<<16,256,0,stream>>>(Wne + it*197632 + 512*256, WeT + it*65536, 256, 256, 4);
  k_transpose_bf16<<<48,256,0,stream>>>(Wch, WchT, 768, 256, 12);
  k_transpose_bf16<<<16,256,0,stream>>>(Wc2, Wc2T, 256, 256, 4);
  k_wsem<<<64,256,0,stream>>>(Wsem, WsemT);

  k_exists<<<256,256,0,stream>>>(cf,Wex,bex,ex_out,ok,flag);
  k_ab<<<128,256,0,stream>>>(cf,Wel,a_,b2_,b2T);
  if (use_elp) k_elpack<<<1024,256,0,stream>>>(a_,b2_,bel,elp);
  k_ee_part<<<512,256,0,stream>>>(a_,b2T,bel,Wee,pee);
  k_ee_combine<<<256,256,0,stream>>>(pee,bee,ok,eem,ee_out,flag);
  for (int it = 0; it < 2; ++it){
    k_sd<<<128,256,0,stream>>>(cf,Wne,bne,sp_,dmat,it);
    if (use_elp)
      k_fused_elp<<<1024,256,0,stream>>>(elp,WeT + it*65536,sp_,dmat,eem,
                                         Wne + it*197632,cf,cfcb,flag,it);
    else
      k_fused_rec<<<1024,256,0,stream>>>(a_,bel,b2_,WeT + it*65536,sp_,dmat,eem,
                                         Wne + it*197632,cf,cfcb,flag,it);
  }
  k_final_mfma<<<16,256,0,stream>>>(cfcb,WchT,bch,Wc2T,bc2,WsemT,bsem,feats_out,sem_out);
}